// Round 2
// baseline (2230.981 us; speedup 1.0000x reference)
//
#include <hip/hip_runtime.h>
#include <hip/hip_bf16.h>
#include <cstdint>
#include <cstddef>

#define S_FRAMES 32
#define P_TOK    196
#define H_HEADS  16
#define D_HEAD   64
#define C_DIM    1024
#define N_TOK    (S_FRAMES * P_TOK)   // 6272
#define MK_TOK   1960
#define LN_EPS   1e-6f
#define SM_SCALE 0.125f               // 1/sqrt(64)

// ---------------------------------------------------------------------------
// GEMM: C[M,N] = A[M,K] @ B[K,N] + bias[N]   (fp32, 64x64 tile, BK=16)
// 256 threads, each computes a 4x4 micro-tile.
// ---------------------------------------------------------------------------
__global__ __launch_bounds__(256) void sgemm_bias_kernel(
    const float* __restrict__ A, const float* __restrict__ B,
    const float* __restrict__ bias, float* __restrict__ C,
    int M, int N, int K)
{
  constexpr int BM = 64, BN = 64, BK = 16;
  __shared__ alignas(16) float As[BK][BM + 4];   // As[k][m]
  __shared__ alignas(16) float Bs[BK][BN + 4];   // Bs[k][n]

  const int tid = threadIdx.x;
  const int bm = blockIdx.y * BM;
  const int bn = blockIdx.x * BN;
  const int tx = tid & 15;        // output col group
  const int ty = tid >> 4;        // output row group

  // A-load mapping: row ar (0..63), k-offset ak (0,4,8,12)
  const int ar = tid >> 2;
  const int ak = (tid & 3) * 4;
  // B-load mapping: k-row br (0..15), col bc (0..60 step 4)
  const int br = tid >> 4;
  const int bc = (tid & 15) * 4;

  float acc[4][4] = {};

  for (int k0 = 0; k0 < K; k0 += BK) {
    __syncthreads();
    float4 av = *(const float4*)(A + (size_t)(bm + ar) * K + k0 + ak);
    As[ak + 0][ar] = av.x;
    As[ak + 1][ar] = av.y;
    As[ak + 2][ar] = av.z;
    As[ak + 3][ar] = av.w;
    *(float4*)&Bs[br][bc] = *(const float4*)(B + (size_t)(k0 + br) * N + bn + bc);
    __syncthreads();

    #pragma unroll
    for (int kk = 0; kk < BK; ++kk) {
      float4 a4 = *(const float4*)&As[kk][ty * 4];
      float4 b4 = *(const float4*)&Bs[kk][tx * 4];
      float aa[4] = {a4.x, a4.y, a4.z, a4.w};
      float bb[4] = {b4.x, b4.y, b4.z, b4.w};
      #pragma unroll
      for (int i = 0; i < 4; ++i)
        #pragma unroll
        for (int j = 0; j < 4; ++j)
          acc[i][j] = fmaf(aa[i], bb[j], acc[i][j]);
    }
  }

  #pragma unroll
  for (int i = 0; i < 4; ++i) {
    float4 o;
    o.x = acc[i][0] + bias[bn + tx * 4 + 0];
    o.y = acc[i][1] + bias[bn + tx * 4 + 1];
    o.z = acc[i][2] + bias[bn + tx * 4 + 2];
    o.w = acc[i][3] + bias[bn + tx * 4 + 3];
    *(float4*)(C + (size_t)(bm + ty * 4 + i) * N + bn + tx * 4) = o;
  }
}

// ---------------------------------------------------------------------------
// Per-(token,head) LayerNorm over D=64 for q and k, in place in qkv.
// One block = 128 threads = 2 waves: wave0 -> q row, wave1 -> k row.
// ---------------------------------------------------------------------------
__global__ __launch_bounds__(128) void qk_ln_kernel(
    float* __restrict__ qkv,
    const float* __restrict__ qg, const float* __restrict__ qb,
    const float* __restrict__ kg, const float* __restrict__ kb)
{
  const int r = blockIdx.x;              // [0, N*H)
  const int n = r / H_HEADS;
  const int h = r % H_HEADS;
  const int wave = threadIdx.x >> 6;     // 0 = q, 1 = k
  const int lane = threadIdx.x & 63;

  float* p = qkv + (size_t)n * (3 * C_DIM) + wave * C_DIM + h * D_HEAD + lane;
  float v = *p;

  float sum = v;
  #pragma unroll
  for (int off = 32; off; off >>= 1) sum += __shfl_xor(sum, off, 64);
  float mu = sum * (1.0f / 64.0f);
  float d = v - mu;

  float vs = d * d;
  #pragma unroll
  for (int off = 32; off; off >>= 1) vs += __shfl_xor(vs, off, 64);
  float var = vs * (1.0f / 64.0f);

  float rstd = rsqrtf(var + LN_EPS);
  const float* g = wave ? kg : qg;
  const float* b = wave ? kb : qb;
  *p = d * rstd * g[lane] + b[lane];
}

// ---------------------------------------------------------------------------
// Sparse attention: one block per (frame s, head h). 256 threads; thread t
// owns query row p=t (p<196). K/V chunks of 64 keys staged in LDS (gathered),
// online softmax per row in registers.
// ---------------------------------------------------------------------------
__global__ __launch_bounds__(256) void sparse_attn_kernel(
    const float* __restrict__ qkv,
    const int*   __restrict__ gather_idx,
    const float* __restrict__ attn_bias,
    float* __restrict__ attn_out)
{
  constexpr int KC = 64;
  __shared__ alignas(16) float Ks[KC][D_HEAD + 4];
  __shared__ alignas(16) float Vs[KC][D_HEAD + 4];
  __shared__ float biasS[KC];

  const int s = blockIdx.x >> 4;     // frame
  const int h = blockIdx.x & 15;     // head
  const int tid = threadIdx.x;
  const int p = tid;
  const bool active = (p < P_TOK);

  const int*   gi = gather_idx + (size_t)s * MK_TOK;
  const float* bi = attn_bias + (size_t)s * MK_TOK;

  // load this thread's q row into registers
  const int qrow = s * P_TOK + (active ? p : 0);
  const float* qptr = qkv + (size_t)qrow * (3 * C_DIM) + h * D_HEAD;
  float q[D_HEAD];
  #pragma unroll
  for (int c = 0; c < 16; ++c) {
    float4 t4 = *(const float4*)(qptr + 4 * c);
    q[4 * c + 0] = t4.x; q[4 * c + 1] = t4.y;
    q[4 * c + 2] = t4.z; q[4 * c + 3] = t4.w;
  }

  float m = -3.0e38f;
  float l = 0.0f;
  float acc[D_HEAD] = {};

  const int jld = tid & 63;        // key slot this thread stages
  const int cpart = tid >> 6;      // which 16-float d-chunk (0..3)

  for (int j0 = 0; j0 < MK_TOK; j0 += KC) {
    const int jn = min(KC, MK_TOK - j0);
    __syncthreads();
    if (jld < jn) {
      const int idx = gi[j0 + jld];
      const float* kbp = qkv + (size_t)idx * (3 * C_DIM) + C_DIM + h * D_HEAD + cpart * 16;
      const float* vbp = kbp + C_DIM;
      #pragma unroll
      for (int u = 0; u < 4; ++u) {
        *(float4*)&Ks[jld][cpart * 16 + 4 * u] = *(const float4*)(kbp + 4 * u);
        *(float4*)&Vs[jld][cpart * 16 + 4 * u] = *(const float4*)(vbp + 4 * u);
      }
    }
    if (tid < jn) biasS[tid] = bi[j0 + tid];
    __syncthreads();

    for (int j = 0; j < jn; ++j) {
      // score = (q . K[j]) * scale + bias
      float s0 = 0.f, s1 = 0.f, s2 = 0.f, s3 = 0.f;
      #pragma unroll
      for (int c = 0; c < 16; ++c) {
        float4 kv = *(const float4*)&Ks[j][4 * c];
        s0 = fmaf(q[4 * c + 0], kv.x, s0);
        s1 = fmaf(q[4 * c + 1], kv.y, s1);
        s2 = fmaf(q[4 * c + 2], kv.z, s2);
        s3 = fmaf(q[4 * c + 3], kv.w, s3);
      }
      float sc = (s0 + s1) + (s2 + s3);
      sc = sc * SM_SCALE + biasS[j];

      if (sc > m) {          // rare: rescale running state
        float al = __expf(m - sc);
        l *= al;
        #pragma unroll
        for (int d = 0; d < D_HEAD; ++d) acc[d] *= al;
        m = sc;
      }
      float pe = __expf(sc - m);
      l += pe;
      #pragma unroll
      for (int c = 0; c < 16; ++c) {
        float4 vv = *(const float4*)&Vs[j][4 * c];
        acc[4 * c + 0] = fmaf(pe, vv.x, acc[4 * c + 0]);
        acc[4 * c + 1] = fmaf(pe, vv.y, acc[4 * c + 1]);
        acc[4 * c + 2] = fmaf(pe, vv.z, acc[4 * c + 2]);
        acc[4 * c + 3] = fmaf(pe, vv.w, acc[4 * c + 3]);
      }
    }
  }

  if (active) {
    const float inv = 1.0f / l;
    float* op = attn_out + (size_t)(s * P_TOK + p) * C_DIM + h * D_HEAD;
    #pragma unroll
    for (int c = 0; c < 16; ++c) {
      float4 o;
      o.x = acc[4 * c + 0] * inv;
      o.y = acc[4 * c + 1] * inv;
      o.z = acc[4 * c + 2] * inv;
      o.w = acc[4 * c + 3] * inv;
      *(float4*)(op + 4 * c) = o;
    }
  }
}

// ---------------------------------------------------------------------------
extern "C" void kernel_launch(void* const* d_in, const int* in_sizes, int n_in,
                              void* d_out, int out_size, void* d_ws, size_t ws_size,
                              hipStream_t stream)
{
  const float* x      = (const float*)d_in[0];
  const float* W_qkv  = (const float*)d_in[1];
  const float* b_qkv  = (const float*)d_in[2];
  const float* q_g    = (const float*)d_in[3];
  const float* q_b    = (const float*)d_in[4];
  const float* k_g    = (const float*)d_in[5];
  const float* k_b    = (const float*)d_in[6];
  const float* W_proj = (const float*)d_in[7];
  const float* b_proj = (const float*)d_in[8];
  const int*   g_idx  = (const int*)d_in[9];
  const float* a_bias = (const float*)d_in[10];
  float* out = (float*)d_out;

  // workspace: qkv [N, 3C] then attn_out [N, C]
  float* qkv = (float*)d_ws;
  float* attn_out = qkv + (size_t)N_TOK * 3 * C_DIM;

  // 1) qkv = x @ W_qkv + b_qkv
  sgemm_bias_kernel<<<dim3((3 * C_DIM) / 64, N_TOK / 64), 256, 0, stream>>>(
      x, W_qkv, b_qkv, qkv, N_TOK, 3 * C_DIM, C_DIM);

  // 2) per-head LayerNorm of q and k (in place)
  qk_ln_kernel<<<N_TOK * H_HEADS, 128, 0, stream>>>(qkv, q_g, q_b, k_g, k_b);

  // 3) sparse gathered attention -> attn_out [N, C]
  sparse_attn_kernel<<<S_FRAMES * H_HEADS, 256, 0, stream>>>(
      qkv, g_idx, a_bias, attn_out);

  // 4) out = attn_out @ W_proj + b_proj
  sgemm_bias_kernel<<<dim3(C_DIM / 64, N_TOK / 64), 256, 0, stream>>>(
      attn_out, W_proj, b_proj, out, N_TOK, C_DIM, C_DIM);
}

// Round 3
// 1212.522 us; speedup vs baseline: 1.8400x; 1.8400x over previous
//
#include <hip/hip_runtime.h>
#include <hip/hip_bf16.h>
#include <cstdint>
#include <cstddef>

#define S_FRAMES 32
#define P_TOK    196
#define H_HEADS  16
#define D_HEAD   64
#define C_DIM    1024
#define N_TOK    (S_FRAMES * P_TOK)   // 6272
#define MK_TOK   1960
#define LN_EPS   1e-6f
#define SM_SCALE 0.125f               // 1/sqrt(64)

typedef __attribute__((ext_vector_type(8))) short short8;
typedef __attribute__((ext_vector_type(4))) short short4v;
typedef __attribute__((ext_vector_type(4))) float f32x4;

static __device__ __forceinline__ ushort f2bf(float x) {
  union { float f; unsigned u; } c; c.f = x;
  unsigned r = (c.u + 0x7FFFu + ((c.u >> 16) & 1u)) >> 16;
  return (ushort)r;
}
static __device__ __forceinline__ unsigned pack_bf16x2(float a, float b) {
  union { float f; unsigned u; } x, y; x.f = a; y.f = b;
  unsigned lo = (x.u + 0x7FFFu + ((x.u >> 16) & 1u)) >> 16;
  unsigned hi = (y.u + 0x7FFFu + ((y.u >> 16) & 1u)) >> 16;
  return lo | (hi << 16);
}

// ---------------------------------------------------------------------------
// GEMM: C[M,N] = A[M,K] @ B[K,N] + bias[N]   (fp32, 64x64 tile, BK=16)
// ---------------------------------------------------------------------------
__global__ __launch_bounds__(256) void sgemm_bias_kernel(
    const float* __restrict__ A, const float* __restrict__ B,
    const float* __restrict__ bias, float* __restrict__ C,
    int M, int N, int K)
{
  constexpr int BM = 64, BN = 64, BK = 16;
  __shared__ alignas(16) float As[BK][BM + 4];
  __shared__ alignas(16) float Bs[BK][BN + 4];

  const int tid = threadIdx.x;
  const int bm = blockIdx.y * BM;
  const int bn = blockIdx.x * BN;
  const int tx = tid & 15;
  const int ty = tid >> 4;
  const int ar = tid >> 2;
  const int ak = (tid & 3) * 4;
  const int br = tid >> 4;
  const int bc = (tid & 15) * 4;

  float acc[4][4] = {};

  for (int k0 = 0; k0 < K; k0 += BK) {
    __syncthreads();
    float4 av = *(const float4*)(A + (size_t)(bm + ar) * K + k0 + ak);
    As[ak + 0][ar] = av.x;
    As[ak + 1][ar] = av.y;
    As[ak + 2][ar] = av.z;
    As[ak + 3][ar] = av.w;
    *(float4*)&Bs[br][bc] = *(const float4*)(B + (size_t)(k0 + br) * N + bn + bc);
    __syncthreads();

    #pragma unroll
    for (int kk = 0; kk < BK; ++kk) {
      float4 a4 = *(const float4*)&As[kk][ty * 4];
      float4 b4 = *(const float4*)&Bs[kk][tx * 4];
      float aa[4] = {a4.x, a4.y, a4.z, a4.w};
      float bb[4] = {b4.x, b4.y, b4.z, b4.w};
      #pragma unroll
      for (int i = 0; i < 4; ++i)
        #pragma unroll
        for (int j = 0; j < 4; ++j)
          acc[i][j] = fmaf(aa[i], bb[j], acc[i][j]);
    }
  }

  #pragma unroll
  for (int i = 0; i < 4; ++i) {
    float4 o;
    o.x = acc[i][0] + bias[bn + tx * 4 + 0];
    o.y = acc[i][1] + bias[bn + tx * 4 + 1];
    o.z = acc[i][2] + bias[bn + tx * 4 + 2];
    o.w = acc[i][3] + bias[bn + tx * 4 + 3];
    *(float4*)(C + (size_t)(bm + ty * 4 + i) * N + bn + tx * 4) = o;
  }
}

// ---------------------------------------------------------------------------
// Prep: per-(token,head) LayerNorm of q and k -> bf16 in MFMA-friendly layouts
// Qb[h][tok][64], Kb[h][tok][64].  wave0 = q, wave1 = k.
// ---------------------------------------------------------------------------
__global__ __launch_bounds__(128) void qk_ln_bf16_kernel(
    const float* __restrict__ qkv,
    const float* __restrict__ qg, const float* __restrict__ qb,
    const float* __restrict__ kg, const float* __restrict__ kb,
    ushort* __restrict__ Qb, ushort* __restrict__ Kb)
{
  const int r = blockIdx.x;              // [0, N*H)
  const int n = r / H_HEADS;
  const int h = r % H_HEADS;
  const int wave = threadIdx.x >> 6;     // 0 = q, 1 = k
  const int lane = threadIdx.x & 63;

  const float* p = qkv + (size_t)n * (3 * C_DIM) + wave * C_DIM + h * D_HEAD + lane;
  float v = *p;

  float sum = v;
  #pragma unroll
  for (int off = 32; off; off >>= 1) sum += __shfl_xor(sum, off, 64);
  float mu = sum * (1.0f / 64.0f);
  float d = v - mu;

  float vs = d * d;
  #pragma unroll
  for (int off = 32; off; off >>= 1) vs += __shfl_xor(vs, off, 64);
  float var = vs * (1.0f / 64.0f);
  float rstd = rsqrtf(var + LN_EPS);

  const float* g = wave ? kg : qg;
  const float* b = wave ? kb : qb;
  float out = d * rstd * g[lane] + b[lane];

  ushort* dst = (wave ? Kb : Qb) + ((size_t)h * N_TOK + n) * 64 + lane;
  *dst = f2bf(out);
}

// ---------------------------------------------------------------------------
// V transpose: qkv v-slice fp32 [N][..] -> Vtg bf16 [H][64][N]
// ---------------------------------------------------------------------------
__global__ __launch_bounds__(256) void v_transpose_kernel(
    const float* __restrict__ qkv, ushort* __restrict__ Vtg)
{
  __shared__ ushort T[64][72];
  const int t0 = blockIdx.x * 64;
  const int h  = blockIdx.y;
  const int tid = threadIdx.x;

  for (int i = tid; i < 64 * 16; i += 256) {
    int tok = i >> 4, dc = i & 15;
    float4 v = *(const float4*)(qkv + (size_t)(t0 + tok) * (3 * C_DIM) + 2 * C_DIM + h * 64 + dc * 4);
    T[tok][dc * 4 + 0] = f2bf(v.x);
    T[tok][dc * 4 + 1] = f2bf(v.y);
    T[tok][dc * 4 + 2] = f2bf(v.z);
    T[tok][dc * 4 + 3] = f2bf(v.w);
  }
  __syncthreads();
  for (int i = tid; i < 64 * 16; i += 256) {
    int d = i >> 4, tc = i & 15;
    short4v w;
    w[0] = (short)T[tc * 4 + 0][d];
    w[1] = (short)T[tc * 4 + 1][d];
    w[2] = (short)T[tc * 4 + 2][d];
    w[3] = (short)T[tc * 4 + 3][d];
    *(short4v*)(Vtg + ((size_t)(h * 64 + d)) * N_TOK + t0 + tc * 4) = w;
  }
}

// ---------------------------------------------------------------------------
// MFMA sparse attention. Block = (s,h), 512 threads = 8 waves.
// Wave w owns q-tiles {w, w+8 (if <13)} of 13 16-row tiles (208>=196 rows).
// Swapped QK^T (mfma(K, Q^T)) -> S^T frags; fixed-max softmax (scores<=8);
// P through small per-wave LDS to transpose into PV A-frags.
// ---------------------------------------------------------------------------
__global__ __launch_bounds__(512, 4) void attn_mfma_kernel(
    const ushort* __restrict__ Qb, const ushort* __restrict__ Kb,
    const ushort* __restrict__ Vtg,
    const int* __restrict__ gather_idx, const float* __restrict__ attn_bias,
    float* __restrict__ attn_out)
{
  constexpr int KROWS = 224;   // 14 kv-16-tiles (196 valid)
  constexpr int VROW  = 232;   // Vt LDS row stride (elems): 464B, 16B-aligned, conflict-free
  constexpr int PROW  = 40;    // P LDS row stride (shorts): 80B
  __shared__ ushort Ks[KROWS * 64];
  __shared__ ushort Vs[64 * VROW];
  __shared__ ushort Pl[8][16 * PROW];

  const int s = blockIdx.x >> 4;
  const int h = blockIdx.x & 15;
  const int tid = threadIdx.x;
  const int wave = tid >> 6;
  const int lane = tid & 63;
  const int g  = lane >> 4;
  const int lq = lane & 15;
  const int nq = (wave < 5) ? 2 : 1;

  const float KEXP = 0.18033688011112042f;   // SM_SCALE * log2(e)
  const float BEXP = 11.541560327111708f;    // 8 * log2(e)

  f32x4 oacc[2][4];
  #pragma unroll
  for (int t = 0; t < 2; ++t)
    #pragma unroll
    for (int dt = 0; dt < 4; ++dt) {
      oacc[t][dt][0] = 0.f; oacc[t][dt][1] = 0.f;
      oacc[t][dt][2] = 0.f; oacc[t][dt][3] = 0.f;
    }
  float lsum[2] = {0.f, 0.f};

  for (int f = 0; f < 10; ++f) {
    if (attn_bias[(size_t)s * MK_TOK + f * P_TOK] < -1.0e8f) break;
    const int tok0 = gather_idx[(size_t)s * MK_TOK + f * P_TOK];
    __syncthreads();

    // stage K: 224 rows x 8 chunks (8 bf16 = 16B), XOR-swizzled chunk index
    for (int c = tid; c < KROWS * 8; c += 512) {
      const int row = c >> 3, ch = c & 7;
      short8* dst = (short8*)&Ks[row * 64 + ((ch ^ (row & 7)) << 3)];
      if (row < P_TOK) {
        *dst = *(const short8*)(Kb + ((size_t)h * N_TOK + tok0 + row) * 64 + (ch << 3));
      } else {
        short8 z = {0,0,0,0,0,0,0,0};
        *dst = z;
      }
    }
    // stage V^T: 64 d-rows x 56 chunks (4 bf16 = 8B); cols >=196 zeroed
    for (int c = tid; c < 64 * 56; c += 512) {
      const int d = c / 56, ch = c - d * 56;
      short4v* dst = (short4v*)&Vs[d * VROW + (ch << 2)];
      if (ch < 49) {
        *dst = *(const short4v*)(Vtg + ((size_t)(h * 64 + d)) * N_TOK + tok0 + (ch << 2));
      } else {
        short4v z = {0,0,0,0};
        *dst = z;
      }
    }
    __syncthreads();

    #pragma unroll
    for (int t = 0; t < 2; ++t) {
      if (t >= nq) break;
      const int qt = wave + t * 8;
      int qrow = qt * 16 + lq; if (qrow > P_TOK - 1) qrow = P_TOK - 1;
      const ushort* qbase = Qb + ((size_t)h * N_TOK + s * P_TOK + qrow) * 64 + g * 8;
      const short8 qf0 = *(const short8*)(qbase);
      const short8 qf1 = *(const short8*)(qbase + 32);

      for (int kt2 = 0; kt2 < 7; ++kt2) {
        #pragma unroll
        for (int half = 0; half < 2; ++half) {
          const int kt = kt2 * 2 + half;
          f32x4 sacc = {0.f, 0.f, 0.f, 0.f};
          if (kt < 13) {
            const int row = kt * 16 + lq;
            const int sw = row & 7;
            short8 ka0 = *(const short8*)&Ks[row * 64 + ((g ^ sw) << 3)];
            short8 ka1 = *(const short8*)&Ks[row * 64 + (((4 + g) ^ sw) << 3)];
            sacc = __builtin_amdgcn_mfma_f32_16x16x32_bf16(ka0, qf0, sacc, 0, 0, 0);
            sacc = __builtin_amdgcn_mfma_f32_16x16x32_bf16(ka1, qf1, sacc, 0, 0, 0);
          }
          float p[4];
          #pragma unroll
          for (int r = 0; r < 4; ++r) {
            const int kv = kt * 16 + g * 4 + r;
            float e = __builtin_exp2f(fmaf(sacc[r], KEXP, -BEXP));
            p[r] = (kv < P_TOK) ? e : 0.f;
            lsum[t] += p[r];
          }
          ushort* pw = &Pl[wave][lq * PROW + half * 16 + g * 4];
          *(unsigned*)(pw)     = pack_bf16x2(p[0], p[1]);
          *(unsigned*)(pw + 2) = pack_bf16x2(p[2], p[3]);
        }
        const short8 pa = *(const short8*)&Pl[wave][lq * PROW + g * 8];
        #pragma unroll
        for (int dt = 0; dt < 4; ++dt) {
          const short8 vb = *(const short8*)&Vs[(dt * 16 + lq) * VROW + kt2 * 32 + g * 8];
          oacc[t][dt] = __builtin_amdgcn_mfma_f32_16x16x32_bf16(pa, vb, oacc[t][dt], 0, 0, 0);
        }
      }
    }
  }

  // epilogue: reduce l over the 4 lane-groups, normalize, store
  #pragma unroll
  for (int t = 0; t < 2; ++t) {
    if (t >= nq) break;
    const int qt = wave + t * 8;
    float lv = lsum[t];
    lv += __shfl_xor(lv, 16, 64);
    lv += __shfl_xor(lv, 32, 64);   // lanes with same (lane&15) now hold full l[q]
    #pragma unroll
    for (int r = 0; r < 4; ++r) {
      const int qrow = qt * 16 + g * 4 + r;
      const float lr = __shfl(lv, (lane & 48) | (g * 4 + r), 64);
      const float inv = 1.0f / lr;
      if (qrow < P_TOK) {
        float* op = attn_out + ((size_t)(s * P_TOK + qrow)) * C_DIM + h * 64;
        #pragma unroll
        for (int dt = 0; dt < 4; ++dt)
          op[dt * 16 + lq] = oacc[t][dt][r] * inv;
      }
    }
  }
}

// ---------------------------------------------------------------------------
// FALLBACK path (verbatim round-2 kernels) if ws_size is too small
// ---------------------------------------------------------------------------
__global__ __launch_bounds__(128) void qk_ln_kernel(
    float* __restrict__ qkv,
    const float* __restrict__ qg, const float* __restrict__ qb,
    const float* __restrict__ kg, const float* __restrict__ kb)
{
  const int r = blockIdx.x;
  const int n = r / H_HEADS;
  const int h = r % H_HEADS;
  const int wave = threadIdx.x >> 6;
  const int lane = threadIdx.x & 63;

  float* p = qkv + (size_t)n * (3 * C_DIM) + wave * C_DIM + h * D_HEAD + lane;
  float v = *p;
  float sum = v;
  #pragma unroll
  for (int off = 32; off; off >>= 1) sum += __shfl_xor(sum, off, 64);
  float mu = sum * (1.0f / 64.0f);
  float d = v - mu;
  float vs = d * d;
  #pragma unroll
  for (int off = 32; off; off >>= 1) vs += __shfl_xor(vs, off, 64);
  float var = vs * (1.0f / 64.0f);
  float rstd = rsqrtf(var + LN_EPS);
  const float* gg = wave ? kg : qg;
  const float* bb = wave ? kb : qb;
  *p = d * rstd * gg[lane] + bb[lane];
}

__global__ __launch_bounds__(256) void sparse_attn_kernel(
    const float* __restrict__ qkv,
    const int*   __restrict__ gather_idx,
    const float* __restrict__ attn_bias,
    float* __restrict__ attn_out)
{
  constexpr int KC = 64;
  __shared__ alignas(16) float Ksf[KC][D_HEAD + 4];
  __shared__ alignas(16) float Vsf[KC][D_HEAD + 4];
  __shared__ float biasS[KC];

  const int s = blockIdx.x >> 4;
  const int h = blockIdx.x & 15;
  const int tid = threadIdx.x;
  const int p = tid;
  const bool active = (p < P_TOK);

  const int*   gi = gather_idx + (size_t)s * MK_TOK;
  const float* bi = attn_bias + (size_t)s * MK_TOK;

  const int qrow = s * P_TOK + (active ? p : 0);
  const float* qptr = qkv + (size_t)qrow * (3 * C_DIM) + h * D_HEAD;
  float q[D_HEAD];
  #pragma unroll
  for (int c = 0; c < 16; ++c) {
    float4 t4 = *(const float4*)(qptr + 4 * c);
    q[4 * c + 0] = t4.x; q[4 * c + 1] = t4.y;
    q[4 * c + 2] = t4.z; q[4 * c + 3] = t4.w;
  }

  float m = -3.0e38f;
  float l = 0.0f;
  float acc[D_HEAD] = {};
  const int jld = tid & 63;
  const int cpart = tid >> 6;

  for (int j0 = 0; j0 < MK_TOK; j0 += KC) {
    const int jn = min(KC, MK_TOK - j0);
    __syncthreads();
    if (jld < jn) {
      const int idx = gi[j0 + jld];
      const float* kbp = qkv + (size_t)idx * (3 * C_DIM) + C_DIM + h * D_HEAD + cpart * 16;
      const float* vbp = kbp + C_DIM;
      #pragma unroll
      for (int u = 0; u < 4; ++u) {
        *(float4*)&Ksf[jld][cpart * 16 + 4 * u] = *(const float4*)(kbp + 4 * u);
        *(float4*)&Vsf[jld][cpart * 16 + 4 * u] = *(const float4*)(vbp + 4 * u);
      }
    }
    if (tid < jn) biasS[tid] = bi[j0 + tid];
    __syncthreads();

    for (int j = 0; j < jn; ++j) {
      float s0 = 0.f, s1 = 0.f, s2 = 0.f, s3 = 0.f;
      #pragma unroll
      for (int c = 0; c < 16; ++c) {
        float4 kv = *(const float4*)&Ksf[j][4 * c];
        s0 = fmaf(q[4 * c + 0], kv.x, s0);
        s1 = fmaf(q[4 * c + 1], kv.y, s1);
        s2 = fmaf(q[4 * c + 2], kv.z, s2);
        s3 = fmaf(q[4 * c + 3], kv.w, s3);
      }
      float sc = (s0 + s1) + (s2 + s3);
      sc = sc * SM_SCALE + biasS[j];
      if (sc > m) {
        float al = __expf(m - sc);
        l *= al;
        #pragma unroll
        for (int d = 0; d < D_HEAD; ++d) acc[d] *= al;
        m = sc;
      }
      float pe = __expf(sc - m);
      l += pe;
      #pragma unroll
      for (int c = 0; c < 16; ++c) {
        float4 vv = *(const float4*)&Vsf[j][4 * c];
        acc[4 * c + 0] = fmaf(pe, vv.x, acc[4 * c + 0]);
        acc[4 * c + 1] = fmaf(pe, vv.y, acc[4 * c + 1]);
        acc[4 * c + 2] = fmaf(pe, vv.z, acc[4 * c + 2]);
        acc[4 * c + 3] = fmaf(pe, vv.w, acc[4 * c + 3]);
      }
    }
  }

  if (active) {
    const float inv = 1.0f / l;
    float* op = attn_out + (size_t)(s * P_TOK + p) * C_DIM + h * D_HEAD;
    #pragma unroll
    for (int c = 0; c < 16; ++c) {
      float4 o;
      o.x = acc[4 * c + 0] * inv;
      o.y = acc[4 * c + 1] * inv;
      o.z = acc[4 * c + 2] * inv;
      o.w = acc[4 * c + 3] * inv;
      *(float4*)(op + 4 * c) = o;
    }
  }
}

// ---------------------------------------------------------------------------
extern "C" void kernel_launch(void* const* d_in, const int* in_sizes, int n_in,
                              void* d_out, int out_size, void* d_ws, size_t ws_size,
                              hipStream_t stream)
{
  const float* x      = (const float*)d_in[0];
  const float* W_qkv  = (const float*)d_in[1];
  const float* b_qkv  = (const float*)d_in[2];
  const float* q_g    = (const float*)d_in[3];
  const float* q_b    = (const float*)d_in[4];
  const float* k_g    = (const float*)d_in[5];
  const float* k_b    = (const float*)d_in[6];
  const float* W_proj = (const float*)d_in[7];
  const float* b_proj = (const float*)d_in[8];
  const int*   g_idx  = (const int*)d_in[9];
  const float* a_bias = (const float*)d_in[10];
  float* out = (float*)d_out;

  float* qkv      = (float*)d_ws;                                  // [N][3072] fp32
  float* attn_out = qkv + (size_t)N_TOK * 3 * C_DIM;               // [N][1024] fp32

  const size_t need = (size_t)N_TOK * 3 * C_DIM * 4                // qkv
                    + (size_t)N_TOK * C_DIM * 4                    // attn_out
                    + (size_t)H_HEADS * D_HEAD * N_TOK * 2;        // Vtg bf16

  // 1) qkv = x @ W_qkv + b_qkv (fp32)
  sgemm_bias_kernel<<<dim3((3 * C_DIM) / 64, N_TOK / 64), 256, 0, stream>>>(
      x, W_qkv, b_qkv, qkv, N_TOK, 3 * C_DIM, C_DIM);

  if (ws_size >= need) {
    // bf16 MFMA path. Qb/Kb live in d_out (exactly N*C*4 bytes), Vtg after attn_out.
    ushort* Qb  = (ushort*)d_out;
    ushort* Kb  = Qb + (size_t)H_HEADS * N_TOK * 64;
    ushort* Vtg = (ushort*)(attn_out + (size_t)N_TOK * C_DIM);

    qk_ln_bf16_kernel<<<N_TOK * H_HEADS, 128, 0, stream>>>(
        qkv, q_g, q_b, k_g, k_b, Qb, Kb);
    v_transpose_kernel<<<dim3(N_TOK / 64, H_HEADS), 256, 0, stream>>>(qkv, Vtg);
    attn_mfma_kernel<<<S_FRAMES * H_HEADS, 512, 0, stream>>>(
        Qb, Kb, Vtg, g_idx, a_bias, attn_out);
  } else {
    // fallback: round-2 fp32 path (needs only qkv + attn_out)
    qk_ln_kernel<<<N_TOK * H_HEADS, 128, 0, stream>>>(qkv, q_g, q_b, k_g, k_b);
    sparse_attn_kernel<<<S_FRAMES * H_HEADS, 256, 0, stream>>>(
        qkv, g_idx, a_bias, attn_out);
  }

  // 4) out = attn_out @ W_proj + b_proj (fp32) — overwrites Qb/Kb scratch in d_out
  sgemm_bias_kernel<<<dim3(C_DIM / 64, N_TOK / 64), 256, 0, stream>>>(
      attn_out, W_proj, b_proj, out, N_TOK, C_DIM, C_DIM);
}

// Round 4
// 735.061 us; speedup vs baseline: 3.0351x; 1.6496x over previous
//
#include <hip/hip_runtime.h>
#include <hip/hip_bf16.h>
#include <cstdint>
#include <cstddef>

#define S_FRAMES 32
#define P_TOK    196
#define H_HEADS  16
#define D_HEAD   64
#define C_DIM    1024
#define N_TOK    (S_FRAMES * P_TOK)   // 6272
#define MK_TOK   1960
#define LN_EPS   1e-6f
#define SM_SCALE 0.125f               // 1/sqrt(64)

typedef __attribute__((ext_vector_type(8))) short short8;
typedef __attribute__((ext_vector_type(4))) short short4v;
typedef __attribute__((ext_vector_type(4))) float f32x4;

static __device__ __forceinline__ ushort f2bf(float x) {
  union { float f; unsigned u; } c; c.f = x;
  unsigned r = (c.u + 0x7FFFu + ((c.u >> 16) & 1u)) >> 16;
  return (ushort)r;
}
static __device__ __forceinline__ float bf2f(ushort h) {
  union { unsigned u; float f; } c; c.u = ((unsigned)h) << 16;
  return c.f;
}
static __device__ __forceinline__ unsigned pack_bf16x2(float a, float b) {
  union { float f; unsigned u; } x, y; x.f = a; y.f = b;
  unsigned lo = (x.u + 0x7FFFu + ((x.u >> 16) & 1u)) >> 16;
  unsigned hi = (y.u + 0x7FFFu + ((y.u >> 16) & 1u)) >> 16;
  return lo | (hi << 16);
}

// ---------------------------------------------------------------------------
// W transpose + hi/lo split:  W [K][Nn] fp32  ->  Bth/Btl [Nn][K] bf16
// ---------------------------------------------------------------------------
__global__ __launch_bounds__(256) void wsplit_kernel(
    const float* __restrict__ W, ushort* __restrict__ Bth,
    ushort* __restrict__ Btl, int K, int Nn)
{
  __shared__ float T[64][72];
  const int n0 = blockIdx.x * 64;
  const int k0 = blockIdx.y * 64;
  const int tid = threadIdx.x;

  for (int idx = tid; idx < 64 * 16; idx += 256) {
    int r = idx >> 4, c4 = idx & 15;
    *(float4*)&T[r][c4 * 4] = *(const float4*)(W + (size_t)(k0 + r) * Nn + n0 + c4 * 4);
  }
  __syncthreads();
  for (int idx = tid; idx < 64 * 8; idx += 256) {
    int nr = idx >> 3, ch = idx & 7;
    short8 hi, lo;
    #pragma unroll
    for (int u = 0; u < 8; ++u) {
      float v = T[ch * 8 + u][nr];
      ushort h = f2bf(v);
      hi[u] = (short)h;
      lo[u] = (short)f2bf(v - bf2f(h));
    }
    *(short8*)(Bth + (size_t)(n0 + nr) * K + k0 + ch * 8) = hi;
    *(short8*)(Btl + (size_t)(n0 + nr) * K + k0 + ch * 8) = lo;
  }
}

// ---------------------------------------------------------------------------
// Split-bf16 3-product MFMA GEMM: C = A @ Bt^T + bias   (fp32 accuracy)
//   A: AMODE 0 -> fp32 [M][K] (split inline);  AMODE 1 -> bf16 hi/lo [M][K]
//   Bt: bf16 hi/lo [N][K]  (i.e. B transposed)
// Epilogue: EMODE 0 -> fp32 C[M][N] + bias
//           EMODE 1 -> fused q/k LayerNorm -> Qb/Kb bf16 [h][tok][64];
//                      v -> Vtg bf16 [h*64+d][tok]  (transposed write)
// Tile 128x128, BK=64, 4 waves (2x2 of 64x64), 16x16x32 bf16 MFMA.
// LDS tiles XOR-swizzled: 16B chunk slot = chunk ^ (row&7)  -> 2-way (free).
// ---------------------------------------------------------------------------
template <int AMODE, int EMODE>
__global__ __launch_bounds__(256, 2) void gemm_split3(
    const void* __restrict__ Ap, const void* __restrict__ Ap2,
    const ushort* __restrict__ Bth, const ushort* __restrict__ Btl,
    const float* __restrict__ bias, float* __restrict__ Cout,
    ushort* __restrict__ Qb, ushort* __restrict__ Kb, ushort* __restrict__ Vtg,
    const float* __restrict__ qg, const float* __restrict__ qbet,
    const float* __restrict__ kg, const float* __restrict__ kbet,
    int M, int Nn, int K)
{
  __shared__ ushort Ah[128 * 64];
  __shared__ ushort Al[128 * 64];
  __shared__ ushort Bh[128 * 64];
  __shared__ ushort Bl[128 * 64];

  const int tid  = threadIdx.x;
  const int wave = tid >> 6;
  const int lane = tid & 63;
  const int g    = lane >> 4;
  const int lq   = lane & 15;
  const int bm   = blockIdx.y * 128;
  const int bn   = blockIdx.x * 128;
  const int wm   = (wave >> 1) * 64;
  const int wn   = (wave & 1) * 64;

  f32x4 acc[4][4];
  #pragma unroll
  for (int i = 0; i < 4; ++i)
    #pragma unroll
    for (int j = 0; j < 4; ++j) {
      acc[i][j][0] = 0.f; acc[i][j][1] = 0.f;
      acc[i][j][2] = 0.f; acc[i][j][3] = 0.f;
    }

  for (int k0 = 0; k0 < K; k0 += 64) {
    __syncthreads();
    for (int idx = tid; idx < 128 * 8; idx += 256) {
      const int row = idx >> 3, c = idx & 7;
      const int gc = c ^ (row & 7);           // source k-chunk for slot c
      if (AMODE == 0) {
        const float* ap = (const float*)Ap + (size_t)(bm + row) * K + k0 + gc * 8;
        float4 f0 = *(const float4*)ap;
        float4 f1 = *(const float4*)(ap + 4);
        float v[8] = {f0.x, f0.y, f0.z, f0.w, f1.x, f1.y, f1.z, f1.w};
        short8 hi, lo;
        #pragma unroll
        for (int u = 0; u < 8; ++u) {
          ushort h = f2bf(v[u]);
          hi[u] = (short)h;
          lo[u] = (short)f2bf(v[u] - bf2f(h));
        }
        *(short8*)&Ah[row * 64 + c * 8] = hi;
        *(short8*)&Al[row * 64 + c * 8] = lo;
      } else {
        *(short8*)&Ah[row * 64 + c * 8] =
            *(const short8*)((const ushort*)Ap  + (size_t)(bm + row) * K + k0 + gc * 8);
        *(short8*)&Al[row * 64 + c * 8] =
            *(const short8*)((const ushort*)Ap2 + (size_t)(bm + row) * K + k0 + gc * 8);
      }
      *(short8*)&Bh[row * 64 + c * 8] =
          *(const short8*)(Bth + (size_t)(bn + row) * K + k0 + gc * 8);
      *(short8*)&Bl[row * 64 + c * 8] =
          *(const short8*)(Btl + (size_t)(bn + row) * K + k0 + gc * 8);
    }
    __syncthreads();

    #pragma unroll
    for (int kt = 0; kt < 2; ++kt) {
      short8 ah[4], al[4], bh[4], bl[4];
      #pragma unroll
      for (int mi = 0; mi < 4; ++mi) {
        const int row = wm + mi * 16 + lq;
        const int sl = (kt * 4 + g) ^ (row & 7);
        ah[mi] = *(const short8*)&Ah[row * 64 + sl * 8];
        al[mi] = *(const short8*)&Al[row * 64 + sl * 8];
      }
      #pragma unroll
      for (int ni = 0; ni < 4; ++ni) {
        const int row = wn + ni * 16 + lq;
        const int sl = (kt * 4 + g) ^ (row & 7);
        bh[ni] = *(const short8*)&Bh[row * 64 + sl * 8];
        bl[ni] = *(const short8*)&Bl[row * 64 + sl * 8];
      }
      #pragma unroll
      for (int mi = 0; mi < 4; ++mi)
        #pragma unroll
        for (int ni = 0; ni < 4; ++ni) {
          acc[mi][ni] = __builtin_amdgcn_mfma_f32_16x16x32_bf16(ah[mi], bl[ni], acc[mi][ni], 0, 0, 0);
          acc[mi][ni] = __builtin_amdgcn_mfma_f32_16x16x32_bf16(al[mi], bh[ni], acc[mi][ni], 0, 0, 0);
          acc[mi][ni] = __builtin_amdgcn_mfma_f32_16x16x32_bf16(ah[mi], bh[ni], acc[mi][ni], 0, 0, 0);
        }
    }
  }

  const int col0 = bn + wn;
  float bias4[4];
  #pragma unroll
  for (int ni = 0; ni < 4; ++ni) bias4[ni] = bias[col0 + ni * 16 + lq];

  if (EMODE == 0) {
    // plain fp32 + bias
    #pragma unroll
    for (int mi = 0; mi < 4; ++mi)
      #pragma unroll
      for (int r = 0; r < 4; ++r) {
        float* cp = Cout + (size_t)(bm + wm + mi * 16 + g * 4 + r) * Nn + col0;
        #pragma unroll
        for (int ni = 0; ni < 4; ++ni)
          cp[ni * 16 + lq] = acc[mi][ni][r] + bias4[ni];
      }
  } else {
    const int type = col0 >> 10;              // 0=q 1=k 2=v
    const int h    = (col0 & 1023) >> 6;
    if (type < 2) {
      const float* gam = type ? kg : qg;
      const float* bet = type ? kbet : qbet;
      float gm[4], bt[4];
      #pragma unroll
      for (int ni = 0; ni < 4; ++ni) {
        gm[ni] = gam[ni * 16 + lq];
        bt[ni] = bet[ni * 16 + lq];
      }
      ushort* outb = (type ? Kb : Qb);
      #pragma unroll
      for (int mi = 0; mi < 4; ++mi)
        #pragma unroll
        for (int r = 0; r < 4; ++r) {
          float xv[4];
          float s = 0.f;
          #pragma unroll
          for (int ni = 0; ni < 4; ++ni) {
            xv[ni] = acc[mi][ni][r] + bias4[ni];
            s += xv[ni];
          }
          s += __shfl_xor(s, 1, 64);
          s += __shfl_xor(s, 2, 64);
          s += __shfl_xor(s, 4, 64);
          s += __shfl_xor(s, 8, 64);
          const float mu = s * (1.0f / 64.0f);
          float ss = 0.f;
          #pragma unroll
          for (int ni = 0; ni < 4; ++ni) {
            float dd = xv[ni] - mu;
            ss += dd * dd;
          }
          ss += __shfl_xor(ss, 1, 64);
          ss += __shfl_xor(ss, 2, 64);
          ss += __shfl_xor(ss, 4, 64);
          ss += __shfl_xor(ss, 8, 64);
          const float rs = rsqrtf(ss * (1.0f / 64.0f) + LN_EPS);
          const int tok = bm + wm + mi * 16 + g * 4 + r;
          ushort* op = outb + ((size_t)h * N_TOK + tok) * 64;
          #pragma unroll
          for (int ni = 0; ni < 4; ++ni)
            op[ni * 16 + lq] = f2bf((xv[ni] - mu) * rs * gm[ni] + bt[ni]);
        }
    } else {
      // v: plain bias, transposed bf16 write Vtg[h*64+d][tok]
      #pragma unroll
      for (int mi = 0; mi < 4; ++mi) {
        const int tok = bm + wm + mi * 16 + g * 4;
        #pragma unroll
        for (int ni = 0; ni < 4; ++ni) {
          const int d = ni * 16 + lq;
          short4v w;
          #pragma unroll
          for (int r = 0; r < 4; ++r) w[r] = (short)f2bf(acc[mi][ni][r] + bias4[ni]);
          *(short4v*)&Vtg[((size_t)(h * 64 + d)) * N_TOK + tok] = w;
        }
      }
    }
  }
}

// ---------------------------------------------------------------------------
// MFMA sparse attention (round-3 core, epilogue now writes bf16 hi/lo split).
// ---------------------------------------------------------------------------
__global__ __launch_bounds__(512, 4) void attn_mfma_kernel(
    const ushort* __restrict__ Qb, const ushort* __restrict__ Kb,
    const ushort* __restrict__ Vtg,
    const int* __restrict__ gather_idx, const float* __restrict__ attn_bias,
    ushort* __restrict__ Chi, ushort* __restrict__ Clo)
{
  constexpr int KROWS = 224;
  constexpr int VROW  = 232;
  constexpr int PROW  = 40;
  __shared__ ushort Ks[KROWS * 64];
  __shared__ ushort Vs[64 * VROW];
  __shared__ ushort Pl[8][16 * PROW];

  const int s = blockIdx.x >> 4;
  const int h = blockIdx.x & 15;
  const int tid = threadIdx.x;
  const int wave = tid >> 6;
  const int lane = tid & 63;
  const int g  = lane >> 4;
  const int lq = lane & 15;
  const int nq = (wave < 5) ? 2 : 1;

  const float KEXP = 0.18033688011112042f;   // SM_SCALE * log2(e)
  const float BEXP = 11.541560327111708f;    // 8 * log2(e)

  f32x4 oacc[2][4];
  #pragma unroll
  for (int t = 0; t < 2; ++t)
    #pragma unroll
    for (int dt = 0; dt < 4; ++dt) {
      oacc[t][dt][0] = 0.f; oacc[t][dt][1] = 0.f;
      oacc[t][dt][2] = 0.f; oacc[t][dt][3] = 0.f;
    }
  float lsum[2] = {0.f, 0.f};

  for (int f = 0; f < 10; ++f) {
    if (attn_bias[(size_t)s * MK_TOK + f * P_TOK] < -1.0e8f) break;
    const int tok0 = gather_idx[(size_t)s * MK_TOK + f * P_TOK];
    __syncthreads();

    for (int c = tid; c < KROWS * 8; c += 512) {
      const int row = c >> 3, ch = c & 7;
      short8* dst = (short8*)&Ks[row * 64 + ((ch ^ (row & 7)) << 3)];
      if (row < P_TOK) {
        *dst = *(const short8*)(Kb + ((size_t)h * N_TOK + tok0 + row) * 64 + (ch << 3));
      } else {
        short8 z = {0,0,0,0,0,0,0,0};
        *dst = z;
      }
    }
    for (int c = tid; c < 64 * 56; c += 512) {
      const int d = c / 56, ch = c - d * 56;
      short4v* dst = (short4v*)&Vs[d * VROW + (ch << 2)];
      if (ch < 49) {
        *dst = *(const short4v*)(Vtg + ((size_t)(h * 64 + d)) * N_TOK + tok0 + (ch << 2));
      } else {
        short4v z = {0,0,0,0};
        *dst = z;
      }
    }
    __syncthreads();

    #pragma unroll
    for (int t = 0; t < 2; ++t) {
      if (t >= nq) break;
      const int qt = wave + t * 8;
      int qrow = qt * 16 + lq; if (qrow > P_TOK - 1) qrow = P_TOK - 1;
      const ushort* qbase = Qb + ((size_t)h * N_TOK + s * P_TOK + qrow) * 64 + g * 8;
      const short8 qf0 = *(const short8*)(qbase);
      const short8 qf1 = *(const short8*)(qbase + 32);

      for (int kt2 = 0; kt2 < 7; ++kt2) {
        #pragma unroll
        for (int half = 0; half < 2; ++half) {
          const int kt = kt2 * 2 + half;
          f32x4 sacc = {0.f, 0.f, 0.f, 0.f};
          if (kt < 13) {
            const int row = kt * 16 + lq;
            const int sw = row & 7;
            short8 ka0 = *(const short8*)&Ks[row * 64 + ((g ^ sw) << 3)];
            short8 ka1 = *(const short8*)&Ks[row * 64 + (((4 + g) ^ sw) << 3)];
            sacc = __builtin_amdgcn_mfma_f32_16x16x32_bf16(ka0, qf0, sacc, 0, 0, 0);
            sacc = __builtin_amdgcn_mfma_f32_16x16x32_bf16(ka1, qf1, sacc, 0, 0, 0);
          }
          float p[4];
          #pragma unroll
          for (int r = 0; r < 4; ++r) {
            const int kv = kt * 16 + g * 4 + r;
            float e = __builtin_exp2f(fmaf(sacc[r], KEXP, -BEXP));
            p[r] = (kv < P_TOK) ? e : 0.f;
            lsum[t] += p[r];
          }
          ushort* pw = &Pl[wave][lq * PROW + half * 16 + g * 4];
          *(unsigned*)(pw)     = pack_bf16x2(p[0], p[1]);
          *(unsigned*)(pw + 2) = pack_bf16x2(p[2], p[3]);
        }
        const short8 pa = *(const short8*)&Pl[wave][lq * PROW + g * 8];
        #pragma unroll
        for (int dt = 0; dt < 4; ++dt) {
          const short8 vb = *(const short8*)&Vs[(dt * 16 + lq) * VROW + kt2 * 32 + g * 8];
          oacc[t][dt] = __builtin_amdgcn_mfma_f32_16x16x32_bf16(pa, vb, oacc[t][dt], 0, 0, 0);
        }
      }
    }
  }

  #pragma unroll
  for (int t = 0; t < 2; ++t) {
    if (t >= nq) break;
    const int qt = wave + t * 8;
    float lv = lsum[t];
    lv += __shfl_xor(lv, 16, 64);
    lv += __shfl_xor(lv, 32, 64);
    #pragma unroll
    for (int r = 0; r < 4; ++r) {
      const int qrow = qt * 16 + g * 4 + r;
      const float lr = __shfl(lv, (lane & 48) | (g * 4 + r), 64);
      const float inv = 1.0f / lr;
      if (qrow < P_TOK) {
        const size_t rowb = ((size_t)(s * P_TOK + qrow)) * C_DIM + h * 64;
        #pragma unroll
        for (int dt = 0; dt < 4; ++dt) {
          float val = oacc[t][dt][r] * inv;
          ushort hi = f2bf(val);
          Chi[rowb + dt * 16 + lq] = hi;
          Clo[rowb + dt * 16 + lq] = f2bf(val - bf2f(hi));
        }
      }
    }
  }
}

// ---------------------------------------------------------------------------
// FALLBACK path (fp32, round-2) if workspace is too small
// ---------------------------------------------------------------------------
__global__ __launch_bounds__(256) void sgemm_bias_kernel(
    const float* __restrict__ A, const float* __restrict__ B,
    const float* __restrict__ bias, float* __restrict__ C,
    int M, int N, int K)
{
  constexpr int BM = 64, BN = 64, BK = 16;
  __shared__ alignas(16) float As[BK][BM + 4];
  __shared__ alignas(16) float Bs[BK][BN + 4];

  const int tid = threadIdx.x;
  const int bm = blockIdx.y * BM;
  const int bn = blockIdx.x * BN;
  const int tx = tid & 15;
  const int ty = tid >> 4;
  const int ar = tid >> 2;
  const int ak = (tid & 3) * 4;
  const int br = tid >> 4;
  const int bc = (tid & 15) * 4;

  float acc[4][4] = {};

  for (int k0 = 0; k0 < K; k0 += BK) {
    __syncthreads();
    float4 av = *(const float4*)(A + (size_t)(bm + ar) * K + k0 + ak);
    As[ak + 0][ar] = av.x;
    As[ak + 1][ar] = av.y;
    As[ak + 2][ar] = av.z;
    As[ak + 3][ar] = av.w;
    *(float4*)&Bs[br][bc] = *(const float4*)(B + (size_t)(k0 + br) * N + bn + bc);
    __syncthreads();

    #pragma unroll
    for (int kk = 0; kk < BK; ++kk) {
      float4 a4 = *(const float4*)&As[kk][ty * 4];
      float4 b4 = *(const float4*)&Bs[kk][tx * 4];
      float aa[4] = {a4.x, a4.y, a4.z, a4.w};
      float bb[4] = {b4.x, b4.y, b4.z, b4.w};
      #pragma unroll
      for (int i = 0; i < 4; ++i)
        #pragma unroll
        for (int j = 0; j < 4; ++j)
          acc[i][j] = fmaf(aa[i], bb[j], acc[i][j]);
    }
  }

  #pragma unroll
  for (int i = 0; i < 4; ++i) {
    float4 o;
    o.x = acc[i][0] + bias[bn + tx * 4 + 0];
    o.y = acc[i][1] + bias[bn + tx * 4 + 1];
    o.z = acc[i][2] + bias[bn + tx * 4 + 2];
    o.w = acc[i][3] + bias[bn + tx * 4 + 3];
    *(float4*)(C + (size_t)(bm + ty * 4 + i) * N + bn + tx * 4) = o;
  }
}

__global__ __launch_bounds__(128) void qk_ln_kernel(
    float* __restrict__ qkv,
    const float* __restrict__ qg, const float* __restrict__ qb,
    const float* __restrict__ kg, const float* __restrict__ kb)
{
  const int r = blockIdx.x;
  const int n = r / H_HEADS;
  const int h = r % H_HEADS;
  const int wave = threadIdx.x >> 6;
  const int lane = threadIdx.x & 63;

  float* p = qkv + (size_t)n * (3 * C_DIM) + wave * C_DIM + h * D_HEAD + lane;
  float v = *p;
  float sum = v;
  #pragma unroll
  for (int off = 32; off; off >>= 1) sum += __shfl_xor(sum, off, 64);
  float mu = sum * (1.0f / 64.0f);
  float d = v - mu;
  float vs = d * d;
  #pragma unroll
  for (int off = 32; off; off >>= 1) vs += __shfl_xor(vs, off, 64);
  float var = vs * (1.0f / 64.0f);
  float rstd = rsqrtf(var + LN_EPS);
  const float* gg = wave ? kg : qg;
  const float* bb = wave ? kb : qb;
  *p = d * rstd * gg[lane] + bb[lane];
}

__global__ __launch_bounds__(256) void sparse_attn_kernel(
    const float* __restrict__ qkv,
    const int*   __restrict__ gather_idx,
    const float* __restrict__ attn_bias,
    float* __restrict__ attn_out)
{
  constexpr int KC = 64;
  __shared__ alignas(16) float Ksf[KC][D_HEAD + 4];
  __shared__ alignas(16) float Vsf[KC][D_HEAD + 4];
  __shared__ float biasS[KC];

  const int s = blockIdx.x >> 4;
  const int h = blockIdx.x & 15;
  const int tid = threadIdx.x;
  const int p = tid;
  const bool active = (p < P_TOK);

  const int*   gi = gather_idx + (size_t)s * MK_TOK;
  const float* bi = attn_bias + (size_t)s * MK_TOK;

  const int qrow = s * P_TOK + (active ? p : 0);
  const float* qptr = qkv + (size_t)qrow * (3 * C_DIM) + h * D_HEAD;
  float q[D_HEAD];
  #pragma unroll
  for (int c = 0; c < 16; ++c) {
    float4 t4 = *(const float4*)(qptr + 4 * c);
    q[4 * c + 0] = t4.x; q[4 * c + 1] = t4.y;
    q[4 * c + 2] = t4.z; q[4 * c + 3] = t4.w;
  }

  float m = -3.0e38f;
  float l = 0.0f;
  float acc[D_HEAD] = {};
  const int jld = tid & 63;
  const int cpart = tid >> 6;

  for (int j0 = 0; j0 < MK_TOK; j0 += KC) {
    const int jn = min(KC, MK_TOK - j0);
    __syncthreads();
    if (jld < jn) {
      const int idx = gi[j0 + jld];
      const float* kbp = qkv + (size_t)idx * (3 * C_DIM) + C_DIM + h * D_HEAD + cpart * 16;
      const float* vbp = kbp + C_DIM;
      #pragma unroll
      for (int u = 0; u < 4; ++u) {
        *(float4*)&Ksf[jld][cpart * 16 + 4 * u] = *(const float4*)(kbp + 4 * u);
        *(float4*)&Vsf[jld][cpart * 16 + 4 * u] = *(const float4*)(vbp + 4 * u);
      }
    }
    if (tid < jn) biasS[tid] = bi[j0 + tid];
    __syncthreads();

    for (int j = 0; j < jn; ++j) {
      float s0 = 0.f, s1 = 0.f, s2 = 0.f, s3 = 0.f;
      #pragma unroll
      for (int c = 0; c < 16; ++c) {
        float4 kv = *(const float4*)&Ksf[j][4 * c];
        s0 = fmaf(q[4 * c + 0], kv.x, s0);
        s1 = fmaf(q[4 * c + 1], kv.y, s1);
        s2 = fmaf(q[4 * c + 2], kv.z, s2);
        s3 = fmaf(q[4 * c + 3], kv.w, s3);
      }
      float sc = (s0 + s1) + (s2 + s3);
      sc = sc * SM_SCALE + biasS[j];
      if (sc > m) {
        float al = __expf(m - sc);
        l *= al;
        #pragma unroll
        for (int d = 0; d < D_HEAD; ++d) acc[d] *= al;
        m = sc;
      }
      float pe = __expf(sc - m);
      l += pe;
      #pragma unroll
      for (int c = 0; c < 16; ++c) {
        float4 vv = *(const float4*)&Vsf[j][4 * c];
        acc[4 * c + 0] = fmaf(pe, vv.x, acc[4 * c + 0]);
        acc[4 * c + 1] = fmaf(pe, vv.y, acc[4 * c + 1]);
        acc[4 * c + 2] = fmaf(pe, vv.z, acc[4 * c + 2]);
        acc[4 * c + 3] = fmaf(pe, vv.w, acc[4 * c + 3]);
      }
    }
  }

  if (active) {
    const float inv = 1.0f / l;
    float* op = attn_out + (size_t)(s * P_TOK + p) * C_DIM + h * D_HEAD;
    #pragma unroll
    for (int c = 0; c < 16; ++c) {
      float4 o;
      o.x = acc[4 * c + 0] * inv;
      o.y = acc[4 * c + 1] * inv;
      o.z = acc[4 * c + 2] * inv;
      o.w = acc[4 * c + 3] * inv;
      *(float4*)(op + 4 * c) = o;
    }
  }
}

// ---------------------------------------------------------------------------
extern "C" void kernel_launch(void* const* d_in, const int* in_sizes, int n_in,
                              void* d_out, int out_size, void* d_ws, size_t ws_size,
                              hipStream_t stream)
{
  const float* x      = (const float*)d_in[0];
  const float* W_qkv  = (const float*)d_in[1];
  const float* b_qkv  = (const float*)d_in[2];
  const float* q_g    = (const float*)d_in[3];
  const float* q_b    = (const float*)d_in[4];
  const float* k_g    = (const float*)d_in[5];
  const float* k_b    = (const float*)d_in[6];
  const float* W_proj = (const float*)d_in[7];
  const float* b_proj = (const float*)d_in[8];
  const int*   g_idx  = (const int*)d_in[9];
  const float* a_bias = (const float*)d_in[10];
  float* out = (float*)d_out;

  // MFMA-path workspace layout (bf16 ushort units); VS = 16*64*6272 elems
  const size_t VS = (size_t)H_HEADS * D_HEAD * N_TOK;          // 6,422,528 elems
  const size_t WQ = (size_t)3 * C_DIM * C_DIM;                 // 3,145,728 elems
  const size_t WP = (size_t)C_DIM * C_DIM;                     // 1,048,576 elems
  const size_t need_new = (5 * VS + 2 * WQ + 2 * WP) * sizeof(ushort);   // ~81 MB

  if (ws_size >= need_new) {
    ushort* base = (ushort*)d_ws;
    ushort* Vtg  = base;
    ushort* Qb   = base + VS;
    ushort* Kb   = base + 2 * VS;
    ushort* Chi  = base + 3 * VS;
    ushort* Clo  = base + 4 * VS;
    ushort* WqT_h = base + 5 * VS;
    ushort* WqT_l = WqT_h + WQ;
    ushort* WpT_h = WqT_l + WQ;
    ushort* WpT_l = WpT_h + WP;

    // 0) W transpose + split
    wsplit_kernel<<<dim3(48, 16), 256, 0, stream>>>(W_qkv, WqT_h, WqT_l, C_DIM, 3 * C_DIM);
    wsplit_kernel<<<dim3(16, 16), 256, 0, stream>>>(W_proj, WpT_h, WpT_l, C_DIM, C_DIM);

    // 1) QKV GEMM (fp32 A inline-split) + fused LN -> Qb/Kb, v -> Vtg
    gemm_split3<0, 1><<<dim3(24, 49), 256, 0, stream>>>(
        x, nullptr, WqT_h, WqT_l, b_qkv, nullptr,
        Qb, Kb, Vtg, q_g, q_b, k_g, k_b, N_TOK, 3 * C_DIM, C_DIM);

    // 2) attention -> Chi/Clo (bf16 split of attn_out)
    attn_mfma_kernel<<<S_FRAMES * H_HEADS, 512, 0, stream>>>(
        Qb, Kb, Vtg, g_idx, a_bias, Chi, Clo);

    // 3) proj GEMM (presplit A) -> d_out fp32
    gemm_split3<1, 0><<<dim3(8, 49), 256, 0, stream>>>(
        Chi, Clo, WpT_h, WpT_l, b_proj, out,
        nullptr, nullptr, nullptr, nullptr, nullptr, nullptr, nullptr,
        N_TOK, C_DIM, C_DIM);
  } else {
    // fp32 fallback (round-2 path)
    float* qkv      = (float*)d_ws;
    float* attn_out = qkv + (size_t)N_TOK * 3 * C_DIM;
    sgemm_bias_kernel<<<dim3((3 * C_DIM) / 64, N_TOK / 64), 256, 0, stream>>>(
        x, W_qkv, b_qkv, qkv, N_TOK, 3 * C_DIM, C_DIM);
    qk_ln_kernel<<<N_TOK * H_HEADS, 128, 0, stream>>>(qkv, q_g, q_b, k_g, k_b);
    sparse_attn_kernel<<<S_FRAMES * H_HEADS, 256, 0, stream>>>(
        qkv, g_idx, a_bias, attn_out);
    sgemm_bias_kernel<<<dim3(C_DIM / 64, N_TOK / 64), 256, 0, stream>>>(
        attn_out, W_proj, b_proj, out, N_TOK, C_DIM, C_DIM);
  }
}

// Round 5
// 503.345 us; speedup vs baseline: 4.4323x; 1.4604x over previous
//
#include <hip/hip_runtime.h>
#include <hip/hip_bf16.h>
#include <cstdint>
#include <cstddef>

#define S_FRAMES 32
#define P_TOK    196
#define H_HEADS  16
#define D_HEAD   64
#define C_DIM    1024
#define N_TOK    (S_FRAMES * P_TOK)   // 6272
#define MK_TOK   1960
#define LN_EPS   1e-6f
#define SM_SCALE 0.125f               // 1/sqrt(64)

typedef __attribute__((ext_vector_type(8))) short short8;
typedef __attribute__((ext_vector_type(4))) short short4v;
typedef __attribute__((ext_vector_type(4))) float f32x4;

static __device__ __forceinline__ ushort f2bf(float x) {
  union { float f; unsigned u; } c; c.f = x;
  unsigned r = (c.u + 0x7FFFu + ((c.u >> 16) & 1u)) >> 16;
  return (ushort)r;
}
static __device__ __forceinline__ float bf2f(ushort h) {
  union { unsigned u; float f; } c; c.u = ((unsigned)h) << 16;
  return c.f;
}
static __device__ __forceinline__ unsigned pack_bf16x2(float a, float b) {
  union { float f; unsigned u; } x, y; x.f = a; y.f = b;
  unsigned lo = (x.u + 0x7FFFu + ((x.u >> 16) & 1u)) >> 16;
  unsigned hi = (y.u + 0x7FFFu + ((y.u >> 16) & 1u)) >> 16;
  return lo | (hi << 16);
}

// ---------------------------------------------------------------------------
// W transpose + hi/lo split:  W [K][Nn] fp32  ->  Bth/Btl [Nn][K] bf16
// ---------------------------------------------------------------------------
__global__ __launch_bounds__(256) void wsplit_kernel(
    const float* __restrict__ W, ushort* __restrict__ Bth,
    ushort* __restrict__ Btl, int K, int Nn)
{
  __shared__ float T[64][72];
  const int n0 = blockIdx.x * 64;
  const int k0 = blockIdx.y * 64;
  const int tid = threadIdx.x;

  for (int idx = tid; idx < 64 * 16; idx += 256) {
    int r = idx >> 4, c4 = idx & 15;
    *(float4*)&T[r][c4 * 4] = *(const float4*)(W + (size_t)(k0 + r) * Nn + n0 + c4 * 4);
  }
  __syncthreads();
  for (int idx = tid; idx < 64 * 8; idx += 256) {
    int nr = idx >> 3, ch = idx & 7;
    short8 hi, lo;
    #pragma unroll
    for (int u = 0; u < 8; ++u) {
      float v = T[ch * 8 + u][nr];
      ushort h = f2bf(v);
      hi[u] = (short)h;
      lo[u] = (short)f2bf(v - bf2f(h));
    }
    *(short8*)(Bth + (size_t)(n0 + nr) * K + k0 + ch * 8) = hi;
    *(short8*)(Btl + (size_t)(n0 + nr) * K + k0 + ch * 8) = lo;
  }
}

// ---------------------------------------------------------------------------
// Split-bf16 3-product MFMA GEMM: C = A @ Bt^T + bias   (fp32 accuracy)
//   A: AMODE 0 -> fp32 [M][K] (split inline);  AMODE 1 -> bf16 hi/lo [M][K]
//   Bt: bf16 hi/lo [N][K]  (i.e. B transposed)
// Epilogue: EMODE 0 -> fp32 C[M][N] + bias
//           EMODE 1 -> fused q/k LayerNorm -> Qb/Kb bf16 [h][tok][64];
//                      v -> Vtg bf16 [h*64+d][tok]  (transposed write)
// Tile 128x128, BK=64, 4 waves (2x2 of 64x64), 16x16x32 bf16 MFMA.
// LDS tiles XOR-swizzled: 16B chunk slot = chunk ^ (row&7)  -> 2-way (free).
// ---------------------------------------------------------------------------
template <int AMODE, int EMODE>
__global__ __launch_bounds__(256, 2) void gemm_split3(
    const void* __restrict__ Ap, const void* __restrict__ Ap2,
    const ushort* __restrict__ Bth, const ushort* __restrict__ Btl,
    const float* __restrict__ bias, float* __restrict__ Cout,
    ushort* __restrict__ Qb, ushort* __restrict__ Kb, ushort* __restrict__ Vtg,
    const float* __restrict__ qg, const float* __restrict__ qbet,
    const float* __restrict__ kg, const float* __restrict__ kbet,
    int M, int Nn, int K)
{
  __shared__ ushort Ah[128 * 64];
  __shared__ ushort Al[128 * 64];
  __shared__ ushort Bh[128 * 64];
  __shared__ ushort Bl[128 * 64];

  const int tid  = threadIdx.x;
  const int wave = tid >> 6;
  const int lane = tid & 63;
  const int g    = lane >> 4;
  const int lq   = lane & 15;
  const int bm   = blockIdx.y * 128;
  const int bn   = blockIdx.x * 128;
  const int wm   = (wave >> 1) * 64;
  const int wn   = (wave & 1) * 64;

  f32x4 acc[4][4];
  #pragma unroll
  for (int i = 0; i < 4; ++i)
    #pragma unroll
    for (int j = 0; j < 4; ++j) {
      acc[i][j][0] = 0.f; acc[i][j][1] = 0.f;
      acc[i][j][2] = 0.f; acc[i][j][3] = 0.f;
    }

  for (int k0 = 0; k0 < K; k0 += 64) {
    __syncthreads();
    for (int idx = tid; idx < 128 * 8; idx += 256) {
      const int row = idx >> 3, c = idx & 7;
      const int gc = c ^ (row & 7);           // source k-chunk for slot c
      if (AMODE == 0) {
        const float* ap = (const float*)Ap + (size_t)(bm + row) * K + k0 + gc * 8;
        float4 f0 = *(const float4*)ap;
        float4 f1 = *(const float4*)(ap + 4);
        float v[8] = {f0.x, f0.y, f0.z, f0.w, f1.x, f1.y, f1.z, f1.w};
        short8 hi, lo;
        #pragma unroll
        for (int u = 0; u < 8; ++u) {
          ushort h = f2bf(v[u]);
          hi[u] = (short)h;
          lo[u] = (short)f2bf(v[u] - bf2f(h));
        }
        *(short8*)&Ah[row * 64 + c * 8] = hi;
        *(short8*)&Al[row * 64 + c * 8] = lo;
      } else {
        *(short8*)&Ah[row * 64 + c * 8] =
            *(const short8*)((const ushort*)Ap  + (size_t)(bm + row) * K + k0 + gc * 8);
        *(short8*)&Al[row * 64 + c * 8] =
            *(const short8*)((const ushort*)Ap2 + (size_t)(bm + row) * K + k0 + gc * 8);
      }
      *(short8*)&Bh[row * 64 + c * 8] =
          *(const short8*)(Bth + (size_t)(bn + row) * K + k0 + gc * 8);
      *(short8*)&Bl[row * 64 + c * 8] =
          *(const short8*)(Btl + (size_t)(bn + row) * K + k0 + gc * 8);
    }
    __syncthreads();

    #pragma unroll
    for (int kt = 0; kt < 2; ++kt) {
      short8 ah[4], al[4], bh[4], bl[4];
      #pragma unroll
      for (int mi = 0; mi < 4; ++mi) {
        const int row = wm + mi * 16 + lq;
        const int sl = (kt * 4 + g) ^ (row & 7);
        ah[mi] = *(const short8*)&Ah[row * 64 + sl * 8];
        al[mi] = *(const short8*)&Al[row * 64 + sl * 8];
      }
      #pragma unroll
      for (int ni = 0; ni < 4; ++ni) {
        const int row = wn + ni * 16 + lq;
        const int sl = (kt * 4 + g) ^ (row & 7);
        bh[ni] = *(const short8*)&Bh[row * 64 + sl * 8];
        bl[ni] = *(const short8*)&Bl[row * 64 + sl * 8];
      }
      #pragma unroll
      for (int mi = 0; mi < 4; ++mi)
        #pragma unroll
        for (int ni = 0; ni < 4; ++ni) {
          acc[mi][ni] = __builtin_amdgcn_mfma_f32_16x16x32_bf16(ah[mi], bl[ni], acc[mi][ni], 0, 0, 0);
          acc[mi][ni] = __builtin_amdgcn_mfma_f32_16x16x32_bf16(al[mi], bh[ni], acc[mi][ni], 0, 0, 0);
          acc[mi][ni] = __builtin_amdgcn_mfma_f32_16x16x32_bf16(ah[mi], bh[ni], acc[mi][ni], 0, 0, 0);
        }
    }
  }

  const int col0 = bn + wn;
  float bias4[4];
  #pragma unroll
  for (int ni = 0; ni < 4; ++ni) bias4[ni] = bias[col0 + ni * 16 + lq];

  if (EMODE == 0) {
    // plain fp32 + bias
    #pragma unroll
    for (int mi = 0; mi < 4; ++mi)
      #pragma unroll
      for (int r = 0; r < 4; ++r) {
        float* cp = Cout + (size_t)(bm + wm + mi * 16 + g * 4 + r) * Nn + col0;
        #pragma unroll
        for (int ni = 0; ni < 4; ++ni)
          cp[ni * 16 + lq] = acc[mi][ni][r] + bias4[ni];
      }
  } else {
    const int type = col0 >> 10;              // 0=q 1=k 2=v
    const int h    = (col0 & 1023) >> 6;
    if (type < 2) {
      const float* gam = type ? kg : qg;
      const float* bet = type ? kbet : qbet;
      float gm[4], bt[4];
      #pragma unroll
      for (int ni = 0; ni < 4; ++ni) {
        gm[ni] = gam[ni * 16 + lq];
        bt[ni] = bet[ni * 16 + lq];
      }
      ushort* outb = (type ? Kb : Qb);
      #pragma unroll
      for (int mi = 0; mi < 4; ++mi)
        #pragma unroll
        for (int r = 0; r < 4; ++r) {
          float xv[4];
          float s = 0.f;
          #pragma unroll
          for (int ni = 0; ni < 4; ++ni) {
            xv[ni] = acc[mi][ni][r] + bias4[ni];
            s += xv[ni];
          }
          s += __shfl_xor(s, 1, 64);
          s += __shfl_xor(s, 2, 64);
          s += __shfl_xor(s, 4, 64);
          s += __shfl_xor(s, 8, 64);
          const float mu = s * (1.0f / 64.0f);
          float ss = 0.f;
          #pragma unroll
          for (int ni = 0; ni < 4; ++ni) {
            float dd = xv[ni] - mu;
            ss += dd * dd;
          }
          ss += __shfl_xor(ss, 1, 64);
          ss += __shfl_xor(ss, 2, 64);
          ss += __shfl_xor(ss, 4, 64);
          ss += __shfl_xor(ss, 8, 64);
          const float rs = rsqrtf(ss * (1.0f / 64.0f) + LN_EPS);
          const int tok = bm + wm + mi * 16 + g * 4 + r;
          ushort* op = outb + ((size_t)h * N_TOK + tok) * 64;
          #pragma unroll
          for (int ni = 0; ni < 4; ++ni)
            op[ni * 16 + lq] = f2bf((xv[ni] - mu) * rs * gm[ni] + bt[ni]);
        }
    } else {
      // v: plain bias, transposed bf16 write Vtg[h*64+d][tok]
      #pragma unroll
      for (int mi = 0; mi < 4; ++mi) {
        const int tok = bm + wm + mi * 16 + g * 4;
        #pragma unroll
        for (int ni = 0; ni < 4; ++ni) {
          const int d = ni * 16 + lq;
          short4v w;
          #pragma unroll
          for (int r = 0; r < 4; ++r) w[r] = (short)f2bf(acc[mi][ni][r] + bias4[ni]);
          *(short4v*)&Vtg[((size_t)(h * 64 + d)) * N_TOK + tok] = w;
        }
      }
    }
  }
}

// ---------------------------------------------------------------------------
// MFMA sparse attention. Block = (s,h), 512 threads = 8 waves.
// launch_bounds (512,2): 256-reg budget -> NO scratch spills (round-4 lesson:
// (512,4) forced 64 arch VGPRs -> ~1 GB/dispatch spill traffic, 367 us).
// LDS (68.6 KB) caps occupancy at 2 blocks/CU regardless.
// ---------------------------------------------------------------------------
__global__ __launch_bounds__(512, 2) void attn_mfma_kernel(
    const ushort* __restrict__ Qb, const ushort* __restrict__ Kb,
    const ushort* __restrict__ Vtg,
    const int* __restrict__ gather_idx, const float* __restrict__ attn_bias,
    ushort* __restrict__ Chi, ushort* __restrict__ Clo)
{
  constexpr int KROWS = 224;
  constexpr int VROW  = 232;
  constexpr int PROW  = 40;
  __shared__ ushort Ks[KROWS * 64];
  __shared__ ushort Vs[64 * VROW];
  __shared__ ushort Pl[8][16 * PROW];

  const int s = blockIdx.x >> 4;
  const int h = blockIdx.x & 15;
  const int tid = threadIdx.x;
  const int wave = tid >> 6;
  const int lane = tid & 63;
  const int g  = lane >> 4;
  const int lq = lane & 15;
  const int nq = (wave < 5) ? 2 : 1;

  const float KEXP = 0.18033688011112042f;   // SM_SCALE * log2(e)
  const float BEXP = 11.541560327111708f;    // 8 * log2(e)

  // one-time zero of pad regions (K rows >=196, V cols >=196); never rewritten
  for (int c = tid; c < (KROWS - P_TOK) * 8; c += 512) {
    const int row = P_TOK + (c >> 3), ch = c & 7;
    short8 z = {0,0,0,0,0,0,0,0};
    *(short8*)&Ks[row * 64 + (ch << 3)] = z;
  }
  for (int c = tid; c < 64 * 7; c += 512) {
    const int d = c / 7, ch = 49 + (c % 7);
    short4v z = {0,0,0,0};
    *(short4v*)&Vs[d * VROW + (ch << 2)] = z;
  }

  f32x4 oacc[2][4];
  #pragma unroll
  for (int t = 0; t < 2; ++t)
    #pragma unroll
    for (int dt = 0; dt < 4; ++dt) {
      oacc[t][dt][0] = 0.f; oacc[t][dt][1] = 0.f;
      oacc[t][dt][2] = 0.f; oacc[t][dt][3] = 0.f;
    }
  float lsum[2] = {0.f, 0.f};

  for (int f = 0; f < 10; ++f) {
    if (attn_bias[(size_t)s * MK_TOK + f * P_TOK] < -1.0e8f) break;
    const int tok0 = gather_idx[(size_t)s * MK_TOK + f * P_TOK];
    __syncthreads();

    // stage K rows 0..195 (8 chunks of 16B each, XOR-swizzled chunk slot)
    for (int c = tid; c < P_TOK * 8; c += 512) {
      const int row = c >> 3, ch = c & 7;
      *(short8*)&Ks[row * 64 + ((ch ^ (row & 7)) << 3)] =
          *(const short8*)(Kb + ((size_t)h * N_TOK + tok0 + row) * 64 + (ch << 3));
    }
    // stage V^T cols 0..195 (49 chunks of 4 bf16 = 8B per d-row)
    for (int c = tid; c < 64 * 49; c += 512) {
      const int d = c / 49, ch = c - d * 49;
      *(short4v*)&Vs[d * VROW + (ch << 2)] =
          *(const short4v*)(Vtg + ((size_t)(h * 64 + d)) * N_TOK + tok0 + (ch << 2));
    }
    __syncthreads();

    #pragma unroll
    for (int t = 0; t < 2; ++t) {
      if (t >= nq) break;
      const int qt = wave + t * 8;
      int qrow = qt * 16 + lq; if (qrow > P_TOK - 1) qrow = P_TOK - 1;
      const ushort* qbase = Qb + ((size_t)h * N_TOK + s * P_TOK + qrow) * 64 + g * 8;
      const short8 qf0 = *(const short8*)(qbase);
      const short8 qf1 = *(const short8*)(qbase + 32);

      for (int kt2 = 0; kt2 < 7; ++kt2) {
        #pragma unroll
        for (int half = 0; half < 2; ++half) {
          const int kt = kt2 * 2 + half;
          f32x4 sacc = {0.f, 0.f, 0.f, 0.f};
          if (kt < 13) {
            const int row = kt * 16 + lq;
            const int sw = row & 7;
            short8 ka0 = *(const short8*)&Ks[row * 64 + ((g ^ sw) << 3)];
            short8 ka1 = *(const short8*)&Ks[row * 64 + (((4 + g) ^ sw) << 3)];
            sacc = __builtin_amdgcn_mfma_f32_16x16x32_bf16(ka0, qf0, sacc, 0, 0, 0);
            sacc = __builtin_amdgcn_mfma_f32_16x16x32_bf16(ka1, qf1, sacc, 0, 0, 0);
          }
          float p[4];
          #pragma unroll
          for (int r = 0; r < 4; ++r) {
            const int kv = kt * 16 + g * 4 + r;
            float e = __builtin_exp2f(fmaf(sacc[r], KEXP, -BEXP));
            p[r] = (kv < P_TOK) ? e : 0.f;
            lsum[t] += p[r];
          }
          ushort* pw = &Pl[wave][lq * PROW + half * 16 + g * 4];
          *(unsigned*)(pw)     = pack_bf16x2(p[0], p[1]);
          *(unsigned*)(pw + 2) = pack_bf16x2(p[2], p[3]);
        }
        const short8 pa = *(const short8*)&Pl[wave][lq * PROW + g * 8];
        #pragma unroll
        for (int dt = 0; dt < 4; ++dt) {
          const short8 vb = *(const short8*)&Vs[(dt * 16 + lq) * VROW + kt2 * 32 + g * 8];
          oacc[t][dt] = __builtin_amdgcn_mfma_f32_16x16x32_bf16(pa, vb, oacc[t][dt], 0, 0, 0);
        }
      }
    }
  }

  #pragma unroll
  for (int t = 0; t < 2; ++t) {
    if (t >= nq) break;
    const int qt = wave + t * 8;
    float lv = lsum[t];
    lv += __shfl_xor(lv, 16, 64);
    lv += __shfl_xor(lv, 32, 64);
    #pragma unroll
    for (int r = 0; r < 4; ++r) {
      const int qrow = qt * 16 + g * 4 + r;
      const float lr = __shfl(lv, (lane & 48) | (g * 4 + r), 64);
      const float inv = 1.0f / lr;
      if (qrow < P_TOK) {
        const size_t rowb = ((size_t)(s * P_TOK + qrow)) * C_DIM + h * 64;
        #pragma unroll
        for (int dt = 0; dt < 4; ++dt) {
          float val = oacc[t][dt][r] * inv;
          ushort hi = f2bf(val);
          Chi[rowb + dt * 16 + lq] = hi;
          Clo[rowb + dt * 16 + lq] = f2bf(val - bf2f(hi));
        }
      }
    }
  }
}

// ---------------------------------------------------------------------------
// FALLBACK path (fp32, round-2) if workspace is too small
// ---------------------------------------------------------------------------
__global__ __launch_bounds__(256) void sgemm_bias_kernel(
    const float* __restrict__ A, const float* __restrict__ B,
    const float* __restrict__ bias, float* __restrict__ C,
    int M, int N, int K)
{
  constexpr int BM = 64, BN = 64, BK = 16;
  __shared__ alignas(16) float As[BK][BM + 4];
  __shared__ alignas(16) float Bs[BK][BN + 4];

  const int tid = threadIdx.x;
  const int bm = blockIdx.y * BM;
  const int bn = blockIdx.x * BN;
  const int tx = tid & 15;
  const int ty = tid >> 4;
  const int ar = tid >> 2;
  const int ak = (tid & 3) * 4;
  const int br = tid >> 4;
  const int bc = (tid & 15) * 4;

  float acc[4][4] = {};

  for (int k0 = 0; k0 < K; k0 += BK) {
    __syncthreads();
    float4 av = *(const float4*)(A + (size_t)(bm + ar) * K + k0 + ak);
    As[ak + 0][ar] = av.x;
    As[ak + 1][ar] = av.y;
    As[ak + 2][ar] = av.z;
    As[ak + 3][ar] = av.w;
    *(float4*)&Bs[br][bc] = *(const float4*)(B + (size_t)(k0 + br) * N + bn + bc);
    __syncthreads();

    #pragma unroll
    for (int kk = 0; kk < BK; ++kk) {
      float4 a4 = *(const float4*)&As[kk][ty * 4];
      float4 b4 = *(const float4*)&Bs[kk][tx * 4];
      float aa[4] = {a4.x, a4.y, a4.z, a4.w};
      float bb[4] = {b4.x, b4.y, b4.z, b4.w};
      #pragma unroll
      for (int i = 0; i < 4; ++i)
        #pragma unroll
        for (int j = 0; j < 4; ++j)
          acc[i][j] = fmaf(aa[i], bb[j], acc[i][j]);
    }
  }

  #pragma unroll
  for (int i = 0; i < 4; ++i) {
    float4 o;
    o.x = acc[i][0] + bias[bn + tx * 4 + 0];
    o.y = acc[i][1] + bias[bn + tx * 4 + 1];
    o.z = acc[i][2] + bias[bn + tx * 4 + 2];
    o.w = acc[i][3] + bias[bn + tx * 4 + 3];
    *(float4*)(C + (size_t)(bm + ty * 4 + i) * N + bn + tx * 4) = o;
  }
}

__global__ __launch_bounds__(128) void qk_ln_kernel(
    float* __restrict__ qkv,
    const float* __restrict__ qg, const float* __restrict__ qb,
    const float* __restrict__ kg, const float* __restrict__ kb)
{
  const int r = blockIdx.x;
  const int n = r / H_HEADS;
  const int h = r % H_HEADS;
  const int wave = threadIdx.x >> 6;
  const int lane = threadIdx.x & 63;

  float* p = qkv + (size_t)n * (3 * C_DIM) + wave * C_DIM + h * D_HEAD + lane;
  float v = *p;
  float sum = v;
  #pragma unroll
  for (int off = 32; off; off >>= 1) sum += __shfl_xor(sum, off, 64);
  float mu = sum * (1.0f / 64.0f);
  float d = v - mu;
  float vs = d * d;
  #pragma unroll
  for (int off = 32; off; off >>= 1) vs += __shfl_xor(vs, off, 64);
  float var = vs * (1.0f / 64.0f);
  float rstd = rsqrtf(var + LN_EPS);
  const float* gg = wave ? kg : qg;
  const float* bb = wave ? kb : qb;
  *p = d * rstd * gg[lane] + bb[lane];
}

__global__ __launch_bounds__(256) void sparse_attn_kernel(
    const float* __restrict__ qkv,
    const int*   __restrict__ gather_idx,
    const float* __restrict__ attn_bias,
    float* __restrict__ attn_out)
{
  constexpr int KC = 64;
  __shared__ alignas(16) float Ksf[KC][D_HEAD + 4];
  __shared__ alignas(16) float Vsf[KC][D_HEAD + 4];
  __shared__ float biasS[KC];

  const int s = blockIdx.x >> 4;
  const int h = blockIdx.x & 15;
  const int tid = threadIdx.x;
  const int p = tid;
  const bool active = (p < P_TOK);

  const int*   gi = gather_idx + (size_t)s * MK_TOK;
  const float* bi = attn_bias + (size_t)s * MK_TOK;

  const int qrow = s * P_TOK + (active ? p : 0);
  const float* qptr = qkv + (size_t)qrow * (3 * C_DIM) + h * D_HEAD;
  float q[D_HEAD];
  #pragma unroll
  for (int c = 0; c < 16; ++c) {
    float4 t4 = *(const float4*)(qptr + 4 * c);
    q[4 * c + 0] = t4.x; q[4 * c + 1] = t4.y;
    q[4 * c + 2] = t4.z; q[4 * c + 3] = t4.w;
  }

  float m = -3.0e38f;
  float l = 0.0f;
  float acc[D_HEAD] = {};
  const int jld = tid & 63;
  const int cpart = tid >> 6;

  for (int j0 = 0; j0 < MK_TOK; j0 += KC) {
    const int jn = min(KC, MK_TOK - j0);
    __syncthreads();
    if (jld < jn) {
      const int idx = gi[j0 + jld];
      const float* kbp = qkv + (size_t)idx * (3 * C_DIM) + C_DIM + h * D_HEAD + cpart * 16;
      const float* vbp = kbp + C_DIM;
      #pragma unroll
      for (int u = 0; u < 4; ++u) {
        *(float4*)&Ksf[jld][cpart * 16 + 4 * u] = *(const float4*)(kbp + 4 * u);
        *(float4*)&Vsf[jld][cpart * 16 + 4 * u] = *(const float4*)(vbp + 4 * u);
      }
    }
    if (tid < jn) biasS[tid] = bi[j0 + tid];
    __syncthreads();

    for (int j = 0; j < jn; ++j) {
      float s0 = 0.f, s1 = 0.f, s2 = 0.f, s3 = 0.f;
      #pragma unroll
      for (int c = 0; c < 16; ++c) {
        float4 kv = *(const float4*)&Ksf[j][4 * c];
        s0 = fmaf(q[4 * c + 0], kv.x, s0);
        s1 = fmaf(q[4 * c + 1], kv.y, s1);
        s2 = fmaf(q[4 * c + 2], kv.z, s2);
        s3 = fmaf(q[4 * c + 3], kv.w, s3);
      }
      float sc = (s0 + s1) + (s2 + s3);
      sc = sc * SM_SCALE + biasS[j];
      if (sc > m) {
        float al = __expf(m - sc);
        l *= al;
        #pragma unroll
        for (int d = 0; d < D_HEAD; ++d) acc[d] *= al;
        m = sc;
      }
      float pe = __expf(sc - m);
      l += pe;
      #pragma unroll
      for (int c = 0; c < 16; ++c) {
        float4 vv = *(const float4*)&Vsf[j][4 * c];
        acc[4 * c + 0] = fmaf(pe, vv.x, acc[4 * c + 0]);
        acc[4 * c + 1] = fmaf(pe, vv.y, acc[4 * c + 1]);
        acc[4 * c + 2] = fmaf(pe, vv.z, acc[4 * c + 2]);
        acc[4 * c + 3] = fmaf(pe, vv.w, acc[4 * c + 3]);
      }
    }
  }

  if (active) {
    const float inv = 1.0f / l;
    float* op = attn_out + (size_t)(s * P_TOK + p) * C_DIM + h * D_HEAD;
    #pragma unroll
    for (int c = 0; c < 16; ++c) {
      float4 o;
      o.x = acc[4 * c + 0] * inv;
      o.y = acc[4 * c + 1] * inv;
      o.z = acc[4 * c + 2] * inv;
      o.w = acc[4 * c + 3] * inv;
      *(float4*)(op + 4 * c) = o;
    }
  }
}

// ---------------------------------------------------------------------------
extern "C" void kernel_launch(void* const* d_in, const int* in_sizes, int n_in,
                              void* d_out, int out_size, void* d_ws, size_t ws_size,
                              hipStream_t stream)
{
  const float* x      = (const float*)d_in[0];
  const float* W_qkv  = (const float*)d_in[1];
  const float* b_qkv  = (const float*)d_in[2];
  const float* q_g    = (const float*)d_in[3];
  const float* q_b    = (const float*)d_in[4];
  const float* k_g    = (const float*)d_in[5];
  const float* k_b    = (const float*)d_in[6];
  const float* W_proj = (const float*)d_in[7];
  const float* b_proj = (const float*)d_in[8];
  const int*   g_idx  = (const int*)d_in[9];
  const float* a_bias = (const float*)d_in[10];
  float* out = (float*)d_out;

  // MFMA-path workspace layout (bf16 ushort units); VS = 16*64*6272 elems
  const size_t VS = (size_t)H_HEADS * D_HEAD * N_TOK;          // 6,422,528 elems
  const size_t WQ = (size_t)3 * C_DIM * C_DIM;                 // 3,145,728 elems
  const size_t WP = (size_t)C_DIM * C_DIM;                     // 1,048,576 elems
  const size_t need_new = (5 * VS + 2 * WQ + 2 * WP) * sizeof(ushort);   // ~81 MB

  if (ws_size >= need_new) {
    ushort* base = (ushort*)d_ws;
    ushort* Vtg  = base;
    ushort* Qb   = base + VS;
    ushort* Kb   = base + 2 * VS;
    ushort* Chi  = base + 3 * VS;
    ushort* Clo  = base + 4 * VS;
    ushort* WqT_h = base + 5 * VS;
    ushort* WqT_l = WqT_h + WQ;
    ushort* WpT_h = WqT_l + WQ;
    ushort* WpT_l = WpT_h + WP;

    // 0) W transpose + split
    wsplit_kernel<<<dim3(48, 16), 256, 0, stream>>>(W_qkv, WqT_h, WqT_l, C_DIM, 3 * C_DIM);
    wsplit_kernel<<<dim3(16, 16), 256, 0, stream>>>(W_proj, WpT_h, WpT_l, C_DIM, C_DIM);

    // 1) QKV GEMM (fp32 A inline-split) + fused LN -> Qb/Kb, v -> Vtg
    gemm_split3<0, 1><<<dim3(24, 49), 256, 0, stream>>>(
        x, nullptr, WqT_h, WqT_l, b_qkv, nullptr,
        Qb, Kb, Vtg, q_g, q_b, k_g, k_b, N_TOK, 3 * C_DIM, C_DIM);

    // 2) attention -> Chi/Clo (bf16 split of attn_out)
    attn_mfma_kernel<<<S_FRAMES * H_HEADS, 512, 0, stream>>>(
        Qb, Kb, Vtg, g_idx, a_bias, Chi, Clo);

    // 3) proj GEMM (presplit A) -> d_out fp32
    gemm_split3<1, 0><<<dim3(8, 49), 256, 0, stream>>>(
        Chi, Clo, WpT_h, WpT_l, b_proj, out,
        nullptr, nullptr, nullptr, nullptr, nullptr, nullptr, nullptr,
        N_TOK, C_DIM, C_DIM);
  } else {
    // fp32 fallback (round-2 path)
    float* qkv      = (float*)d_ws;
    float* attn_out = qkv + (size_t)N_TOK * 3 * C_DIM;
    sgemm_bias_kernel<<<dim3((3 * C_DIM) / 64, N_TOK / 64), 256, 0, stream>>>(
        x, W_qkv, b_qkv, qkv, N_TOK, 3 * C_DIM, C_DIM);
    qk_ln_kernel<<<N_TOK * H_HEADS, 128, 0, stream>>>(qkv, q_g, q_b, k_g, k_b);
    sparse_attn_kernel<<<S_FRAMES * H_HEADS, 256, 0, stream>>>(
        qkv, g_idx, a_bias, attn_out);
    sgemm_bias_kernel<<<dim3(C_DIM / 64, N_TOK / 64), 256, 0, stream>>>(
        attn_out, W_proj, b_proj, out, N_TOK, C_DIM, C_DIM);
  }
}

// Round 6
// 436.057 us; speedup vs baseline: 5.1163x; 1.1543x over previous
//
#include <hip/hip_runtime.h>
#include <hip/hip_bf16.h>
#include <cstdint>
#include <cstddef>

#define S_FRAMES 32
#define P_TOK    196
#define H_HEADS  16
#define D_HEAD   64
#define C_DIM    1024
#define N_TOK    (S_FRAMES * P_TOK)   // 6272
#define MK_TOK   1960
#define LN_EPS   1e-6f
#define SM_SCALE 0.125f               // 1/sqrt(64)

typedef __attribute__((ext_vector_type(8))) short short8;
typedef __attribute__((ext_vector_type(4))) short short4v;
typedef __attribute__((ext_vector_type(4))) float f32x4;

static __device__ __forceinline__ ushort f2bf(float x) {
  union { float f; unsigned u; } c; c.f = x;
  unsigned r = (c.u + 0x7FFFu + ((c.u >> 16) & 1u)) >> 16;
  return (ushort)r;
}
static __device__ __forceinline__ float bf2f(ushort h) {
  union { unsigned u; float f; } c; c.u = ((unsigned)h) << 16;
  return c.f;
}
static __device__ __forceinline__ unsigned pack_bf16x2(float a, float b) {
  union { float f; unsigned u; } x, y; x.f = a; y.f = b;
  unsigned lo = (x.u + 0x7FFFu + ((x.u >> 16) & 1u)) >> 16;
  unsigned hi = (y.u + 0x7FFFu + ((y.u >> 16) & 1u)) >> 16;
  return lo | (hi << 16);
}

// async global->LDS 16B per lane; LDS dest is wave-uniform base + lane*16
#define GLOAD16(g, l) __builtin_amdgcn_global_load_lds( \
    (const __attribute__((address_space(1))) void*)(g), \
    (__attribute__((address_space(3))) void*)(l), 16, 0, 0)

// ---------------------------------------------------------------------------
// W transpose + hi/lo split:  W [K][Nn] fp32  ->  Bth/Btl [Nn][K] bf16
// ---------------------------------------------------------------------------
__global__ __launch_bounds__(256) void wsplit_kernel(
    const float* __restrict__ W, ushort* __restrict__ Bth,
    ushort* __restrict__ Btl, int K, int Nn)
{
  __shared__ float T[64][72];
  const int n0 = blockIdx.x * 64;
  const int k0 = blockIdx.y * 64;
  const int tid = threadIdx.x;

  for (int idx = tid; idx < 64 * 16; idx += 256) {
    int r = idx >> 4, c4 = idx & 15;
    *(float4*)&T[r][c4 * 4] = *(const float4*)(W + (size_t)(k0 + r) * Nn + n0 + c4 * 4);
  }
  __syncthreads();
  for (int idx = tid; idx < 64 * 8; idx += 256) {
    int nr = idx >> 3, ch = idx & 7;
    short8 hi, lo;
    #pragma unroll
    for (int u = 0; u < 8; ++u) {
      float v = T[ch * 8 + u][nr];
      ushort h = f2bf(v);
      hi[u] = (short)h;
      lo[u] = (short)f2bf(v - bf2f(h));
    }
    *(short8*)(Bth + (size_t)(n0 + nr) * K + k0 + ch * 8) = hi;
    *(short8*)(Btl + (size_t)(n0 + nr) * K + k0 + ch * 8) = lo;
  }
}

// ---------------------------------------------------------------------------
// x split (same layout, elementwise): x fp32 [N][K] -> Xh/Xl bf16 [N][K]
// ---------------------------------------------------------------------------
__global__ __launch_bounds__(256) void xsplit_kernel(
    const float* __restrict__ x, ushort* __restrict__ Xh,
    ushort* __restrict__ Xl, int n4)
{
  for (int i = blockIdx.x * 256 + threadIdx.x; i < n4; i += gridDim.x * 256) {
    float4 v = ((const float4*)x)[i];
    float vv[4] = {v.x, v.y, v.z, v.w};
    short4v h, lo;
    #pragma unroll
    for (int u = 0; u < 4; ++u) {
      ushort hb = f2bf(vv[u]);
      h[u] = (short)hb;
      lo[u] = (short)f2bf(vv[u] - bf2f(hb));
    }
    ((short4v*)Xh)[i] = h;
    ((short4v*)Xl)[i] = lo;
  }
}

// ---------------------------------------------------------------------------
// Split-bf16 3-product MFMA GEMM: C = A @ Bt^T + bias   (fp32 accuracy)
//   A: bf16 hi/lo [M][K] (pre-split);  Bt: bf16 hi/lo [N][K]
// Staging via global_load_lds width-16 (round-6): linear LDS dest, source
// chunk pre-swizzled gc = c ^ (row&7), swizzle reapplied on fragment read.
// Epilogue: EMODE 0 -> fp32 C[M][N] + bias
//           EMODE 1 -> fused q/k LayerNorm -> Qb/Kb bf16 [h][tok][64];
//                      v -> Vtg bf16 [h*64+d][tok]  (transposed write)
// Tile 128x128, BK=64, 4 waves (2x2 of 64x64), 16x16x32 bf16 MFMA.
// ---------------------------------------------------------------------------
template <int EMODE>
__global__ __launch_bounds__(256, 2) void gemm_split3(
    const ushort* __restrict__ Ah_g, const ushort* __restrict__ Al_g,
    const ushort* __restrict__ Bth, const ushort* __restrict__ Btl,
    const float* __restrict__ bias, float* __restrict__ Cout,
    ushort* __restrict__ Qb, ushort* __restrict__ Kb, ushort* __restrict__ Vtg,
    const float* __restrict__ qg, const float* __restrict__ qbet,
    const float* __restrict__ kg, const float* __restrict__ kbet,
    int M, int Nn, int K)
{
  __shared__ ushort Ah[128 * 64];
  __shared__ ushort Al[128 * 64];
  __shared__ ushort Bh[128 * 64];
  __shared__ ushort Bl[128 * 64];

  const int tid  = threadIdx.x;
  const int wave = tid >> 6;
  const int lane = tid & 63;
  const int g    = lane >> 4;
  const int lq   = lane & 15;
  const int bm   = blockIdx.y * 128;
  const int bn   = blockIdx.x * 128;
  const int wm   = (wave >> 1) * 64;
  const int wn   = (wave & 1) * 64;

  // per-lane global source offsets for the 4 staging rounds (8 rows/wave each);
  // lane l covers tile-row trow = wave*8 + i*32 + (l>>3), chunk gc = (l&7)^(trow&7)
  size_t offA[4], offB[4];
  unsigned ldsoff[4];                 // wave-uniform: slot (wave*64+i*256)*8 ushorts
  #pragma unroll
  for (int i = 0; i < 4; ++i) {
    const int tr = wave * 8 + i * 32 + (lane >> 3);
    const int gc = (lane & 7) ^ (tr & 7);
    offA[i] = (size_t)(bm + tr) * K + gc * 8;
    offB[i] = (size_t)(bn + tr) * K + gc * 8;
    ldsoff[i] = (unsigned)(wave * 512 + i * 2048);
  }

  f32x4 acc[4][4];
  #pragma unroll
  for (int i = 0; i < 4; ++i)
    #pragma unroll
    for (int j = 0; j < 4; ++j) {
      acc[i][j][0] = 0.f; acc[i][j][1] = 0.f;
      acc[i][j][2] = 0.f; acc[i][j][3] = 0.f;
    }

  for (int k0 = 0; k0 < K; k0 += 64) {
    __syncthreads();
    #pragma unroll
    for (int i = 0; i < 4; ++i) {
      GLOAD16(Ah_g + offA[i] + k0, &Ah[ldsoff[i]]);
      GLOAD16(Al_g + offA[i] + k0, &Al[ldsoff[i]]);
      GLOAD16(Bth  + offB[i] + k0, &Bh[ldsoff[i]]);
      GLOAD16(Btl  + offB[i] + k0, &Bl[ldsoff[i]]);
    }
    __syncthreads();   // compiler drains vmcnt(0) before barrier

    #pragma unroll
    for (int kt = 0; kt < 2; ++kt) {
      short8 ah[4], al[4], bh[4], bl[4];
      #pragma unroll
      for (int mi = 0; mi < 4; ++mi) {
        const int row = wm + mi * 16 + lq;
        const int sl = (kt * 4 + g) ^ (row & 7);
        ah[mi] = *(const short8*)&Ah[row * 64 + sl * 8];
        al[mi] = *(const short8*)&Al[row * 64 + sl * 8];
      }
      #pragma unroll
      for (int ni = 0; ni < 4; ++ni) {
        const int row = wn + ni * 16 + lq;
        const int sl = (kt * 4 + g) ^ (row & 7);
        bh[ni] = *(const short8*)&Bh[row * 64 + sl * 8];
        bl[ni] = *(const short8*)&Bl[row * 64 + sl * 8];
      }
      #pragma unroll
      for (int mi = 0; mi < 4; ++mi)
        #pragma unroll
        for (int ni = 0; ni < 4; ++ni) {
          acc[mi][ni] = __builtin_amdgcn_mfma_f32_16x16x32_bf16(ah[mi], bl[ni], acc[mi][ni], 0, 0, 0);
          acc[mi][ni] = __builtin_amdgcn_mfma_f32_16x16x32_bf16(al[mi], bh[ni], acc[mi][ni], 0, 0, 0);
          acc[mi][ni] = __builtin_amdgcn_mfma_f32_16x16x32_bf16(ah[mi], bh[ni], acc[mi][ni], 0, 0, 0);
        }
    }
  }

  const int col0 = bn + wn;
  float bias4[4];
  #pragma unroll
  for (int ni = 0; ni < 4; ++ni) bias4[ni] = bias[col0 + ni * 16 + lq];

  if (EMODE == 0) {
    #pragma unroll
    for (int mi = 0; mi < 4; ++mi)
      #pragma unroll
      for (int r = 0; r < 4; ++r) {
        float* cp = Cout + (size_t)(bm + wm + mi * 16 + g * 4 + r) * Nn + col0;
        #pragma unroll
        for (int ni = 0; ni < 4; ++ni)
          cp[ni * 16 + lq] = acc[mi][ni][r] + bias4[ni];
      }
  } else {
    const int type = col0 >> 10;              // 0=q 1=k 2=v
    const int h    = (col0 & 1023) >> 6;
    if (type < 2) {
      const float* gam = type ? kg : qg;
      const float* bet = type ? kbet : qbet;
      float gm[4], bt[4];
      #pragma unroll
      for (int ni = 0; ni < 4; ++ni) {
        gm[ni] = gam[ni * 16 + lq];
        bt[ni] = bet[ni * 16 + lq];
      }
      ushort* outb = (type ? Kb : Qb);
      #pragma unroll
      for (int mi = 0; mi < 4; ++mi)
        #pragma unroll
        for (int r = 0; r < 4; ++r) {
          float xv[4];
          float s = 0.f;
          #pragma unroll
          for (int ni = 0; ni < 4; ++ni) {
            xv[ni] = acc[mi][ni][r] + bias4[ni];
            s += xv[ni];
          }
          s += __shfl_xor(s, 1, 64);
          s += __shfl_xor(s, 2, 64);
          s += __shfl_xor(s, 4, 64);
          s += __shfl_xor(s, 8, 64);
          const float mu = s * (1.0f / 64.0f);
          float ss = 0.f;
          #pragma unroll
          for (int ni = 0; ni < 4; ++ni) {
            float dd = xv[ni] - mu;
            ss += dd * dd;
          }
          ss += __shfl_xor(ss, 1, 64);
          ss += __shfl_xor(ss, 2, 64);
          ss += __shfl_xor(ss, 4, 64);
          ss += __shfl_xor(ss, 8, 64);
          const float rs = rsqrtf(ss * (1.0f / 64.0f) + LN_EPS);
          const int tok = bm + wm + mi * 16 + g * 4 + r;
          ushort* op = outb + ((size_t)h * N_TOK + tok) * 64;
          #pragma unroll
          for (int ni = 0; ni < 4; ++ni)
            op[ni * 16 + lq] = f2bf((xv[ni] - mu) * rs * gm[ni] + bt[ni]);
        }
    } else {
      // v: plain bias, transposed bf16 write Vtg[h*64+d][tok]
      #pragma unroll
      for (int mi = 0; mi < 4; ++mi) {
        const int tok = bm + wm + mi * 16 + g * 4;
        #pragma unroll
        for (int ni = 0; ni < 4; ++ni) {
          const int d = ni * 16 + lq;
          short4v w;
          #pragma unroll
          for (int r = 0; r < 4; ++r) w[r] = (short)f2bf(acc[mi][ni][r] + bias4[ni]);
          *(short4v*)&Vtg[((size_t)(h * 64 + d)) * N_TOK + tok] = w;
        }
      }
    }
  }
}

// ---------------------------------------------------------------------------
// MFMA sparse attention. Block = (s,h), 512 threads = 8 waves.
// launch_bounds (512,2): 256-reg budget -> no spills (round-4 lesson).
// ---------------------------------------------------------------------------
__global__ __launch_bounds__(512, 2) void attn_mfma_kernel(
    const ushort* __restrict__ Qb, const ushort* __restrict__ Kb,
    const ushort* __restrict__ Vtg,
    const int* __restrict__ gather_idx, const float* __restrict__ attn_bias,
    ushort* __restrict__ Chi, ushort* __restrict__ Clo)
{
  constexpr int KROWS = 224;
  constexpr int VROW  = 232;
  constexpr int PROW  = 40;
  __shared__ ushort Ks[KROWS * 64];
  __shared__ ushort Vs[64 * VROW];
  __shared__ ushort Pl[8][16 * PROW];

  const int s = blockIdx.x >> 4;
  const int h = blockIdx.x & 15;
  const int tid = threadIdx.x;
  const int wave = tid >> 6;
  const int lane = tid & 63;
  const int g  = lane >> 4;
  const int lq = lane & 15;
  const int nq = (wave < 5) ? 2 : 1;

  const float KEXP = 0.18033688011112042f;   // SM_SCALE * log2(e)
  const float BEXP = 11.541560327111708f;    // 8 * log2(e)

  // one-time zero of pad regions (K rows >=196, V cols >=196)
  for (int c = tid; c < (KROWS - P_TOK) * 8; c += 512) {
    const int row = P_TOK + (c >> 3), ch = c & 7;
    short8 z = {0,0,0,0,0,0,0,0};
    *(short8*)&Ks[row * 64 + (ch << 3)] = z;
  }
  for (int c = tid; c < 64 * 7; c += 512) {
    const int d = c / 7, ch = 49 + (c % 7);
    short4v z = {0,0,0,0};
    *(short4v*)&Vs[d * VROW + (ch << 2)] = z;
  }

  f32x4 oacc[2][4];
  #pragma unroll
  for (int t = 0; t < 2; ++t)
    #pragma unroll
    for (int dt = 0; dt < 4; ++dt) {
      oacc[t][dt][0] = 0.f; oacc[t][dt][1] = 0.f;
      oacc[t][dt][2] = 0.f; oacc[t][dt][3] = 0.f;
    }
  float lsum[2] = {0.f, 0.f};

  for (int f = 0; f < 10; ++f) {
    if (attn_bias[(size_t)s * MK_TOK + f * P_TOK] < -1.0e8f) break;
    const int tok0 = gather_idx[(size_t)s * MK_TOK + f * P_TOK];
    __syncthreads();

    for (int c = tid; c < P_TOK * 8; c += 512) {
      const int row = c >> 3, ch = c & 7;
      *(short8*)&Ks[row * 64 + ((ch ^ (row & 7)) << 3)] =
          *(const short8*)(Kb + ((size_t)h * N_TOK + tok0 + row) * 64 + (ch << 3));
    }
    for (int c = tid; c < 64 * 49; c += 512) {
      const int d = c / 49, ch = c - d * 49;
      *(short4v*)&Vs[d * VROW + (ch << 2)] =
          *(const short4v*)(Vtg + ((size_t)(h * 64 + d)) * N_TOK + tok0 + (ch << 2));
    }
    __syncthreads();

    #pragma unroll
    for (int t = 0; t < 2; ++t) {
      if (t >= nq) break;
      const int qt = wave + t * 8;
      int qrow = qt * 16 + lq; if (qrow > P_TOK - 1) qrow = P_TOK - 1;
      const ushort* qbase = Qb + ((size_t)h * N_TOK + s * P_TOK + qrow) * 64 + g * 8;
      const short8 qf0 = *(const short8*)(qbase);
      const short8 qf1 = *(const short8*)(qbase + 32);

      for (int kt2 = 0; kt2 < 7; ++kt2) {
        #pragma unroll
        for (int half = 0; half < 2; ++half) {
          const int kt = kt2 * 2 + half;
          f32x4 sacc = {0.f, 0.f, 0.f, 0.f};
          if (kt < 13) {
            const int row = kt * 16 + lq;
            const int sw = row & 7;
            short8 ka0 = *(const short8*)&Ks[row * 64 + ((g ^ sw) << 3)];
            short8 ka1 = *(const short8*)&Ks[row * 64 + (((4 + g) ^ sw) << 3)];
            sacc = __builtin_amdgcn_mfma_f32_16x16x32_bf16(ka0, qf0, sacc, 0, 0, 0);
            sacc = __builtin_amdgcn_mfma_f32_16x16x32_bf16(ka1, qf1, sacc, 0, 0, 0);
          }
          float p[4];
          #pragma unroll
          for (int r = 0; r < 4; ++r) {
            const int kv = kt * 16 + g * 4 + r;
            float e = __builtin_exp2f(fmaf(sacc[r], KEXP, -BEXP));
            p[r] = (kv < P_TOK) ? e : 0.f;
            lsum[t] += p[r];
          }
          ushort* pw = &Pl[wave][lq * PROW + half * 16 + g * 4];
          *(unsigned*)(pw)     = pack_bf16x2(p[0], p[1]);
          *(unsigned*)(pw + 2) = pack_bf16x2(p[2], p[3]);
        }
        const short8 pa = *(const short8*)&Pl[wave][lq * PROW + g * 8];
        #pragma unroll
        for (int dt = 0; dt < 4; ++dt) {
          const short8 vb = *(const short8*)&Vs[(dt * 16 + lq) * VROW + kt2 * 32 + g * 8];
          oacc[t][dt] = __builtin_amdgcn_mfma_f32_16x16x32_bf16(pa, vb, oacc[t][dt], 0, 0, 0);
        }
      }
    }
  }

  #pragma unroll
  for (int t = 0; t < 2; ++t) {
    if (t >= nq) break;
    const int qt = wave + t * 8;
    float lv = lsum[t];
    lv += __shfl_xor(lv, 16, 64);
    lv += __shfl_xor(lv, 32, 64);
    #pragma unroll
    for (int r = 0; r < 4; ++r) {
      const int qrow = qt * 16 + g * 4 + r;
      const float lr = __shfl(lv, (lane & 48) | (g * 4 + r), 64);
      const float inv = 1.0f / lr;
      if (qrow < P_TOK) {
        const size_t rowb = ((size_t)(s * P_TOK + qrow)) * C_DIM + h * 64;
        #pragma unroll
        for (int dt = 0; dt < 4; ++dt) {
          float val = oacc[t][dt][r] * inv;
          ushort hi = f2bf(val);
          Chi[rowb + dt * 16 + lq] = hi;
          Clo[rowb + dt * 16 + lq] = f2bf(val - bf2f(hi));
        }
      }
    }
  }
}

// ---------------------------------------------------------------------------
// FALLBACK path (fp32, round-2) if workspace is too small
// ---------------------------------------------------------------------------
__global__ __launch_bounds__(256) void sgemm_bias_kernel(
    const float* __restrict__ A, const float* __restrict__ B,
    const float* __restrict__ bias, float* __restrict__ C,
    int M, int N, int K)
{
  constexpr int BM = 64, BN = 64, BK = 16;
  __shared__ alignas(16) float As[BK][BM + 4];
  __shared__ alignas(16) float Bs[BK][BN + 4];

  const int tid = threadIdx.x;
  const int bm = blockIdx.y * BM;
  const int bn = blockIdx.x * BN;
  const int tx = tid & 15;
  const int ty = tid >> 4;
  const int ar = tid >> 2;
  const int ak = (tid & 3) * 4;
  const int br = tid >> 4;
  const int bc = (tid & 15) * 4;

  float acc[4][4] = {};

  for (int k0 = 0; k0 < K; k0 += BK) {
    __syncthreads();
    float4 av = *(const float4*)(A + (size_t)(bm + ar) * K + k0 + ak);
    As[ak + 0][ar] = av.x;
    As[ak + 1][ar] = av.y;
    As[ak + 2][ar] = av.z;
    As[ak + 3][ar] = av.w;
    *(float4*)&Bs[br][bc] = *(const float4*)(B + (size_t)(k0 + br) * N + bn + bc);
    __syncthreads();

    #pragma unroll
    for (int kk = 0; kk < BK; ++kk) {
      float4 a4 = *(const float4*)&As[kk][ty * 4];
      float4 b4 = *(const float4*)&Bs[kk][tx * 4];
      float aa[4] = {a4.x, a4.y, a4.z, a4.w};
      float bb[4] = {b4.x, b4.y, b4.z, b4.w};
      #pragma unroll
      for (int i = 0; i < 4; ++i)
        #pragma unroll
        for (int j = 0; j < 4; ++j)
          acc[i][j] = fmaf(aa[i], bb[j], acc[i][j]);
    }
  }

  #pragma unroll
  for (int i = 0; i < 4; ++i) {
    float4 o;
    o.x = acc[i][0] + bias[bn + tx * 4 + 0];
    o.y = acc[i][1] + bias[bn + tx * 4 + 1];
    o.z = acc[i][2] + bias[bn + tx * 4 + 2];
    o.w = acc[i][3] + bias[bn + tx * 4 + 3];
    *(float4*)(C + (size_t)(bm + ty * 4 + i) * N + bn + tx * 4) = o;
  }
}

__global__ __launch_bounds__(128) void qk_ln_kernel(
    float* __restrict__ qkv,
    const float* __restrict__ qg, const float* __restrict__ qb,
    const float* __restrict__ kg, const float* __restrict__ kb)
{
  const int r = blockIdx.x;
  const int n = r / H_HEADS;
  const int h = r % H_HEADS;
  const int wave = threadIdx.x >> 6;
  const int lane = threadIdx.x & 63;

  float* p = qkv + (size_t)n * (3 * C_DIM) + wave * C_DIM + h * D_HEAD + lane;
  float v = *p;
  float sum = v;
  #pragma unroll
  for (int off = 32; off; off >>= 1) sum += __shfl_xor(sum, off, 64);
  float mu = sum * (1.0f / 64.0f);
  float d = v - mu;
  float vs = d * d;
  #pragma unroll
  for (int off = 32; off; off >>= 1) vs += __shfl_xor(vs, off, 64);
  float var = vs * (1.0f / 64.0f);
  float rstd = rsqrtf(var + LN_EPS);
  const float* gg = wave ? kg : qg;
  const float* bb = wave ? kb : qb;
  *p = d * rstd * gg[lane] + bb[lane];
}

__global__ __launch_bounds__(256) void sparse_attn_kernel(
    const float* __restrict__ qkv,
    const int*   __restrict__ gather_idx,
    const float* __restrict__ attn_bias,
    float* __restrict__ attn_out)
{
  constexpr int KC = 64;
  __shared__ alignas(16) float Ksf[KC][D_HEAD + 4];
  __shared__ alignas(16) float Vsf[KC][D_HEAD + 4];
  __shared__ float biasS[KC];

  const int s = blockIdx.x >> 4;
  const int h = blockIdx.x & 15;
  const int tid = threadIdx.x;
  const int p = tid;
  const bool active = (p < P_TOK);

  const int*   gi = gather_idx + (size_t)s * MK_TOK;
  const float* bi = attn_bias + (size_t)s * MK_TOK;

  const int qrow = s * P_TOK + (active ? p : 0);
  const float* qptr = qkv + (size_t)qrow * (3 * C_DIM) + h * D_HEAD;
  float q[D_HEAD];
  #pragma unroll
  for (int c = 0; c < 16; ++c) {
    float4 t4 = *(const float4*)(qptr + 4 * c);
    q[4 * c + 0] = t4.x; q[4 * c + 1] = t4.y;
    q[4 * c + 2] = t4.z; q[4 * c + 3] = t4.w;
  }

  float m = -3.0e38f;
  float l = 0.0f;
  float acc[D_HEAD] = {};
  const int jld = tid & 63;
  const int cpart = tid >> 6;

  for (int j0 = 0; j0 < MK_TOK; j0 += KC) {
    const int jn = min(KC, MK_TOK - j0);
    __syncthreads();
    if (jld < jn) {
      const int idx = gi[j0 + jld];
      const float* kbp = qkv + (size_t)idx * (3 * C_DIM) + C_DIM + h * D_HEAD + cpart * 16;
      const float* vbp = kbp + C_DIM;
      #pragma unroll
      for (int u = 0; u < 4; ++u) {
        *(float4*)&Ksf[jld][cpart * 16 + 4 * u] = *(const float4*)(kbp + 4 * u);
        *(float4*)&Vsf[jld][cpart * 16 + 4 * u] = *(const float4*)(vbp + 4 * u);
      }
    }
    if (tid < jn) biasS[tid] = bi[j0 + tid];
    __syncthreads();

    for (int j = 0; j < jn; ++j) {
      float s0 = 0.f, s1 = 0.f, s2 = 0.f, s3 = 0.f;
      #pragma unroll
      for (int c = 0; c < 16; ++c) {
        float4 kv = *(const float4*)&Ksf[j][4 * c];
        s0 = fmaf(q[4 * c + 0], kv.x, s0);
        s1 = fmaf(q[4 * c + 1], kv.y, s1);
        s2 = fmaf(q[4 * c + 2], kv.z, s2);
        s3 = fmaf(q[4 * c + 3], kv.w, s3);
      }
      float sc = (s0 + s1) + (s2 + s3);
      sc = sc * SM_SCALE + biasS[j];
      if (sc > m) {
        float al = __expf(m - sc);
        l *= al;
        #pragma unroll
        for (int d = 0; d < D_HEAD; ++d) acc[d] *= al;
        m = sc;
      }
      float pe = __expf(sc - m);
      l += pe;
      #pragma unroll
      for (int c = 0; c < 16; ++c) {
        float4 vv = *(const float4*)&Vsf[j][4 * c];
        acc[4 * c + 0] = fmaf(pe, vv.x, acc[4 * c + 0]);
        acc[4 * c + 1] = fmaf(pe, vv.y, acc[4 * c + 1]);
        acc[4 * c + 2] = fmaf(pe, vv.z, acc[4 * c + 2]);
        acc[4 * c + 3] = fmaf(pe, vv.w, acc[4 * c + 3]);
      }
    }
  }

  if (active) {
    const float inv = 1.0f / l;
    float* op = attn_out + (size_t)(s * P_TOK + p) * C_DIM + h * D_HEAD;
    #pragma unroll
    for (int c = 0; c < 16; ++c) {
      float4 o;
      o.x = acc[4 * c + 0] * inv;
      o.y = acc[4 * c + 1] * inv;
      o.z = acc[4 * c + 2] * inv;
      o.w = acc[4 * c + 3] * inv;
      *(float4*)(op + 4 * c) = o;
    }
  }
}

// ---------------------------------------------------------------------------
extern "C" void kernel_launch(void* const* d_in, const int* in_sizes, int n_in,
                              void* d_out, int out_size, void* d_ws, size_t ws_size,
                              hipStream_t stream)
{
  const float* x      = (const float*)d_in[0];
  const float* W_qkv  = (const float*)d_in[1];
  const float* b_qkv  = (const float*)d_in[2];
  const float* q_g    = (const float*)d_in[3];
  const float* q_b    = (const float*)d_in[4];
  const float* k_g    = (const float*)d_in[5];
  const float* k_b    = (const float*)d_in[6];
  const float* W_proj = (const float*)d_in[7];
  const float* b_proj = (const float*)d_in[8];
  const int*   g_idx  = (const int*)d_in[9];
  const float* a_bias = (const float*)d_in[10];
  float* out = (float*)d_out;

  // MFMA-path workspace (bf16 ushort units); VS = 16*64*6272 = N*C elems.
  // Xh/Xl alias Chi/Clo: Xh/Xl dead after QKV GEMM, Chi/Clo written by attn.
  const size_t VS = (size_t)H_HEADS * D_HEAD * N_TOK;          // 6,422,528 elems
  const size_t WQ = (size_t)3 * C_DIM * C_DIM;
  const size_t WP = (size_t)C_DIM * C_DIM;
  const size_t need_new = (5 * VS + 2 * WQ + 2 * WP) * sizeof(ushort);   // ~81 MB

  if (ws_size >= need_new) {
    ushort* base = (ushort*)d_ws;
    ushort* Vtg  = base;
    ushort* Qb   = base + VS;
    ushort* Kb   = base + 2 * VS;
    ushort* Chi  = base + 3 * VS;    // also Xh before attention
    ushort* Clo  = base + 4 * VS;    // also Xl before attention
    ushort* WqT_h = base + 5 * VS;
    ushort* WqT_l = WqT_h + WQ;
    ushort* WpT_h = WqT_l + WQ;
    ushort* WpT_l = WpT_h + WP;
    ushort* Xh = Chi;
    ushort* Xl = Clo;

    // 0) input splits
    wsplit_kernel<<<dim3(48, 16), 256, 0, stream>>>(W_qkv, WqT_h, WqT_l, C_DIM, 3 * C_DIM);
    wsplit_kernel<<<dim3(16, 16), 256, 0, stream>>>(W_proj, WpT_h, WpT_l, C_DIM, C_DIM);
    xsplit_kernel<<<2048, 256, 0, stream>>>(x, Xh, Xl, N_TOK * C_DIM / 4);

    // 1) QKV GEMM + fused LN -> Qb/Kb, v -> Vtg
    gemm_split3<1><<<dim3(24, 49), 256, 0, stream>>>(
        Xh, Xl, WqT_h, WqT_l, b_qkv, nullptr,
        Qb, Kb, Vtg, q_g, q_b, k_g, k_b, N_TOK, 3 * C_DIM, C_DIM);

    // 2) attention -> Chi/Clo (overwrites Xh/Xl)
    attn_mfma_kernel<<<S_FRAMES * H_HEADS, 512, 0, stream>>>(
        Qb, Kb, Vtg, g_idx, a_bias, Chi, Clo);

    // 3) proj GEMM -> d_out fp32
    gemm_split3<0><<<dim3(8, 49), 256, 0, stream>>>(
        Chi, Clo, WpT_h, WpT_l, b_proj, out,
        nullptr, nullptr, nullptr, nullptr, nullptr, nullptr, nullptr,
        N_TOK, C_DIM, C_DIM);
  } else {
    // fp32 fallback (round-2 path)
    float* qkv      = (float*)d_ws;
    float* attn_out = qkv + (size_t)N_TOK * 3 * C_DIM;
    sgemm_bias_kernel<<<dim3((3 * C_DIM) / 64, N_TOK / 64), 256, 0, stream>>>(
        x, W_qkv, b_qkv, qkv, N_TOK, 3 * C_DIM, C_DIM);
    qk_ln_kernel<<<N_TOK * H_HEADS, 128, 0, stream>>>(qkv, q_g, q_b, k_g, k_b);
    sparse_attn_kernel<<<S_FRAMES * H_HEADS, 256, 0, stream>>>(
        qkv, g_idx, a_bias, attn_out);
    sgemm_bias_kernel<<<dim3(C_DIM / 64, N_TOK / 64), 256, 0, stream>>>(
        attn_out, W_proj, b_proj, out, N_TOK, C_DIM, C_DIM);
  }
}